// Round 6
// baseline (1751.757 us; speedup 1.0000x reference)
//
#include <hip/hip_runtime.h>

// ---------------------------------------------------------------------------
// Transformer (B=2, N=2048, D=1024, H=16, DH=64, DEPTH=4, FF=4, GEGLU, causal)
// R6: attention occupancy 2x (8-wave blocks: 4 waves hi tile + 4 waves lo
// tile, still barrier-free) + defer-max softmax (common path has ZERO
// cross-lane shuffles; l kept as per-lane partial, reduced once at end).
// GEMMs unchanged from R5 (BK=64 counted-vmcnt pipeline, T2 swizzle, T5).
// ---------------------------------------------------------------------------

typedef float f32x4 __attribute__((ext_vector_type(4)));
typedef __bf16 bf16x8 __attribute__((ext_vector_type(8)));
typedef unsigned short u16;
typedef unsigned int u32;

#define SCALE2 0.18033688011112042f   // DH^-0.5 * log2(e)
#define LN_EPS 1e-3f
#define DEFER_THR 8.0f                // log2-domain: P bounded by 2^8

__device__ __forceinline__ float fexp2(float x) { return __builtin_amdgcn_exp2f(x); }

__device__ __forceinline__ u16 f2bf(float f) {
  u32 u = __float_as_uint(f);
  u += 0x7fffu + ((u >> 16) & 1u);   // round-to-nearest-even
  return (u16)(u >> 16);
}

// async global->LDS, 16B/lane; lds base wave-uniform (HW adds lane*16)
__device__ __forceinline__ void stage16(void* lds_wave_base, const void* gsrc) {
  __builtin_amdgcn_global_load_lds((__attribute__((address_space(1))) void*)gsrc,
                                   (__attribute__((address_space(3))) void*)lds_wave_base,
                                   16, 0, 0);
}

// ---------------------------------------------------------------------------
// Weight transpose + cast: W f32 [L][K][N] -> WT bf16 [L][N][K].
// permMode=1 (W1): rows permuted so 16 a-cols / 16 gate-cols alternate.
// ---------------------------------------------------------------------------
__global__ void wtrans_kernel(const float* __restrict__ W, u16* __restrict__ WT,
                              int K, int N, int permMode) {
  __shared__ float tile[32][33];
  const int n0 = blockIdx.x * 32, k0 = blockIdx.y * 32;
  const float* Wl = W + (size_t)blockIdx.z * K * N;
  u16* WTl = WT + (size_t)blockIdx.z * K * N;
  const int tx = threadIdx.x, ty = threadIdx.y;
#pragma unroll
  for (int i = 0; i < 4; ++i)
    tile[ty + i * 8][tx] = Wl[(size_t)(k0 + ty + i * 8) * N + n0 + tx];
  __syncthreads();
#pragma unroll
  for (int i = 0; i < 4; ++i) {
    const int n = n0 + ty + i * 8;
    int orow;
    if (permMode) {
      orow = (n < 4096) ? (((n >> 4) << 5) + (n & 15))
                        : ((((n - 4096) >> 4) << 5) + 16 + (n & 15));
    } else {
      orow = n;
    }
    WTl[(size_t)orow * K + k0 + tx] = f2bf(tile[tx][ty + i * 8]);
  }
}

// V part of qkv -> per-(b,h) transposed V^T [bh][64 d][2048 tok] (bf16)
__global__ void vtrans_kernel(const u16* __restrict__ qkv, u16* __restrict__ Vt) {
  __shared__ u16 tile[32][33];
  const int t0 = blockIdx.x * 32, d0 = blockIdx.y * 32, bh = blockIdx.z;
  const int b = bh >> 4, h = bh & 15;
  const int tx = threadIdx.x, ty = threadIdx.y;
#pragma unroll
  for (int i = 0; i < 4; ++i)
    tile[ty + i * 8][tx] =
        qkv[((size_t)(b * 2048 + t0 + ty + i * 8)) * 3072 + 2048 + h * 64 + d0 + tx];
  __syncthreads();
#pragma unroll
  for (int i = 0; i < 4; ++i)
    Vt[((size_t)bh * 64 + d0 + ty + i * 8) * 2048 + t0 + tx] = tile[tx][ty + i * 8];
}

// ---------------------------------------------------------------------------
// LayerNorm: x f32 [4096][1024] -> y bf16
// ---------------------------------------------------------------------------
__global__ __launch_bounds__(256, 4)
void ln_kernel(const float* __restrict__ x, const float* __restrict__ g,
               const float* __restrict__ b, u16* __restrict__ y) {
  const int row = blockIdx.x, tid = threadIdx.x;
  const float4 v = ((const float4*)(x + (size_t)row * 1024))[tid];
  float s = v.x + v.y + v.z + v.w;
  float s2 = v.x * v.x + v.y * v.y + v.z * v.z + v.w * v.w;
#pragma unroll
  for (int off = 32; off > 0; off >>= 1) {
    s += __shfl_down(s, off);
    s2 += __shfl_down(s2, off);
  }
  __shared__ float ps[8];
  __shared__ float stats[2];
  const int wv = tid >> 6, lane = tid & 63;
  if (lane == 0) { ps[wv] = s; ps[wv + 4] = s2; }
  __syncthreads();
  if (tid == 0) {
    const float S = ps[0] + ps[1] + ps[2] + ps[3];
    const float S2 = ps[4] + ps[5] + ps[6] + ps[7];
    const float mu = S * (1.0f / 1024.0f);
    const float var = S2 * (1.0f / 1024.0f) - mu * mu;
    stats[0] = mu;
    stats[1] = rsqrtf(var + LN_EPS);
  }
  __syncthreads();
  const float mu = stats[0], rs = stats[1];
  const float4 gg = ((const float4*)g)[tid];
  const float4 bb = ((const float4*)b)[tid];
  ushort4 ov;
  ov.x = f2bf((v.x - mu) * rs * gg.x + bb.x);
  ov.y = f2bf((v.y - mu) * rs * gg.y + bb.y);
  ov.z = f2bf((v.z - mu) * rs * gg.z + bb.z);
  ov.w = f2bf((v.w - mu) * rs * gg.w + bb.w);
  ((ushort4*)(y + (size_t)row * 1024))[tid] = ov;
}

// ---------------------------------------------------------------------------
// Pipelined GEMM (R5, unchanged): BK=64, 2 LDS buffers, stage t+2 while t+1
// flies; raw s_barrier (no vmcnt drain) after stage. XOR-swizzled LDS.
// ---------------------------------------------------------------------------
template <int EPI, int BM, int BN, int WM, int WN>
__global__ __launch_bounds__(WM * WN * 64, 2)
void gemm2(const u16* __restrict__ A, const u16* __restrict__ B,
           float* __restrict__ resid, const float* __restrict__ bias,
           u16* __restrict__ out, int M, int N, int K) {
  constexpr int NTHR = WM * WN * 64;
  constexpr int MT = BM / WM / 16;
  constexpr int NT = BN / WN / 16;
  constexpr int QM = MT / 4;
  __shared__ __align__(16) u16 lds[2][(BM + BN) * 64];

  const int tid = threadIdx.x;
  const int wv = tid >> 6, lane = tid & 63;
  const int lr = lane & 15, lg = lane >> 4;
  const int wmi = wv / WN, wni = wv % WN;

  const int nwg = (int)(gridDim.x * gridDim.y);
  int id = (int)(blockIdx.y * gridDim.x + blockIdx.x);
  id = (id & 7) * (nwg >> 3) + (id >> 3);
  const int m0 = (id / (int)gridDim.x) * BM, n0 = (id % (int)gridDim.x) * BN;

  auto stage = [&](int bsel, int k0) {
    u16* dstA = &lds[bsel][0];
    u16* dstB = &lds[bsel][BM * 64];
#pragma unroll
    for (int rnd = 0; rnd < (BM * 128) / (NTHR * 16); ++rnd) {
      const int base = rnd * (NTHR * 16) + wv * 1024;
      const int off = base + lane * 16;
      const int row = off >> 7;
      const int k2 = (off & 127) ^ ((row & 7) << 4);
      stage16((char*)dstA + base, A + (size_t)(m0 + row) * K + k0 + (k2 >> 1));
    }
#pragma unroll
    for (int rnd = 0; rnd < (BN * 128) / (NTHR * 16); ++rnd) {
      const int base = rnd * (NTHR * 16) + wv * 1024;
      const int off = base + lane * 16;
      const int row = off >> 7;
      const int k2 = (off & 127) ^ ((row & 7) << 4);
      stage16((char*)dstB + base, B + (size_t)(n0 + row) * K + k0 + (k2 >> 1));
    }
  };

  f32x4 acc[MT][NT] = {};

  const int nT = K >> 6;
  stage(0, 0);
  stage(1, 64);
  asm volatile("s_waitcnt vmcnt(8)\n\ts_barrier" ::: "memory");

  for (int t = 0; t < nT; ++t) {
    const u16* As = &lds[t & 1][0];
    const u16* Bs = &lds[t & 1][BM * 64];
#pragma unroll
    for (int ks = 0; ks < 2; ++ks) {
      bf16x8 bfr[NT];
#pragma unroll
      for (int nt = 0; nt < NT; ++nt) {
        const int row = wni * (BN / WN) + nt * 16 + lr;
        bfr[nt] = *(const bf16x8*)((const char*)Bs + row * 128 +
                                   ((ks * 64 + lg * 16) ^ ((lr & 7) << 4)));
      }
#pragma unroll
      for (int qm = 0; qm < QM; ++qm) {
        bf16x8 afr[4];
#pragma unroll
        for (int i = 0; i < 4; ++i) {
          const int row = wmi * (BM / WM) + (qm * 4 + i) * 16 + lr;
          afr[i] = *(const bf16x8*)((const char*)As + row * 128 +
                                    ((ks * 64 + lg * 16) ^ ((lr & 7) << 4)));
        }
        __builtin_amdgcn_s_setprio(1);
#pragma unroll
        for (int i = 0; i < 4; ++i)
#pragma unroll
          for (int nt = 0; nt < NT; ++nt)
            acc[qm * 4 + i][nt] = __builtin_amdgcn_mfma_f32_16x16x32_bf16(
                afr[i], bfr[nt], acc[qm * 4 + i][nt], 0, 0, 0);
        __builtin_amdgcn_s_setprio(0);
      }
    }
    __syncthreads();
    if (t + 2 < nT) stage(t & 1, (t + 2) * 64);
    asm volatile("s_barrier" ::: "memory");
  }

  const int RB0 = wmi * (BM / WM), CB0 = wni * (BN / WN);
  if (EPI == 0) {
#pragma unroll
    for (int mt = 0; mt < MT; ++mt)
#pragma unroll
      for (int nt = 0; nt < NT; ++nt) {
        const int n = n0 + CB0 + nt * 16 + lr;
#pragma unroll
        for (int r = 0; r < 4; ++r) {
          const int m = m0 + RB0 + mt * 16 + lg * 4 + r;
          out[(size_t)m * N + n] = f2bf(acc[mt][nt][r]);
        }
      }
  } else if (EPI == 1) {
    float bs[NT];
#pragma unroll
    for (int nt = 0; nt < NT; ++nt) bs[nt] = bias[n0 + CB0 + nt * 16 + lr];
#pragma unroll
    for (int mt = 0; mt < MT; ++mt)
#pragma unroll
      for (int nt = 0; nt < NT; ++nt) {
        const int n = n0 + CB0 + nt * 16 + lr;
#pragma unroll
        for (int r = 0; r < 4; ++r) {
          const int m = m0 + RB0 + mt * 16 + lg * 4 + r;
          resid[(size_t)m * N + n] += acc[mt][nt][r] + bs[nt];
        }
      }
  } else {
#pragma unroll
    for (int pt = 0; pt < NT / 2; ++pt) {
      const int colA = ((n0 + CB0 + pt * 32) >> 5) * 16 + lr;
      const float ba = bias[colA];
      const float bg = bias[4096 + colA];
#pragma unroll
      for (int mt = 0; mt < MT; ++mt)
#pragma unroll
        for (int r = 0; r < 4; ++r) {
          const int m = m0 + RB0 + mt * 16 + lg * 4 + r;
          const float a = acc[mt][2 * pt][r] + ba;
          const float g = acc[mt][2 * pt + 1][r] + bg;
          const float gl = 0.5f * g * (1.0f + erff(g * 0.70710678118654752f));
          out[(size_t)m * 4096 + colA] = f2bf(a * gl);
        }
    }
  }
}

// ---------------------------------------------------------------------------
// Barrier-free causal flash attention, swapped QK^T, 8 waves/block.
// Waves 0-3 own q-tile (31-pr), waves 4-7 own q-tile pr -> block weight is
// uniform (132 wave-iters) and grid (16,32) = 2 blocks/CU all-resident at
// 4 waves/SIMD. Defer-max: common path has no cross-lane ops at all; l kept
// per-lane partial, reduced once in the epilogue.
// ---------------------------------------------------------------------------
__global__ __launch_bounds__(512, 4)
void attn_kernel(const u16* __restrict__ qkv, const u16* __restrict__ Vt,
                 u16* __restrict__ attnout) {
  __shared__ __align__(16) u16 Ps[8][16 * 64];   // wave-private P, 16 KB

  const int tid = threadIdx.x;
  const int wv = tid >> 6, lane = tid & 63;
  const int lr = lane & 15, lg = lane >> 4;
  const int pr = blockIdx.x;                     // 0..15
  const int bh = blockIdx.y;
  const int b = bh >> 4, h = bh & 15;
  const size_t tokbase = (size_t)b * 2048;
  const int qt = (wv < 4) ? (31 - pr) : pr;      // this wave's q-tile
  const int ws = wv & 3;                         // 16-row slice within tile
  const int qg = qt * 64 + ws * 16 + lr;         // this lane's global q row

  // Q fragment (B-operand of swapped QK^T): row = q token, d = ks*32+lg*8
  bf16x8 qf[2];
#pragma unroll
  for (int ks = 0; ks < 2; ++ks)
    qf[ks] = *(const bf16x8*)(qkv + (tokbase + qt * 64 + ws * 16 + lr) * 3072 +
                              h * 64 + ks * 32 + lg * 8);

  f32x4 o[4] = {};
  float m = -1e30f, lp = 0.f;    // running max (q=lr), per-lane partial l

  auto loadK = [&](bf16x8 (&kf)[4][2], int kt) {
#pragma unroll
    for (int nt = 0; nt < 4; ++nt)
#pragma unroll
      for (int ks = 0; ks < 2; ++ks)
        kf[nt][ks] = *(const bf16x8*)(qkv + (tokbase + kt * 64 + nt * 16 + lr) * 3072 +
                                      1024 + h * 64 + ks * 32 + lg * 8);
  };

  auto compute = [&](bf16x8 (&kf)[4][2], int kt) {
    // V^T fragments issued first; consumed after softmax
    bf16x8 vf[4][2];
#pragma unroll
    for (int dt = 0; dt < 4; ++dt)
#pragma unroll
      for (int ks = 0; ks < 2; ++ks)
        vf[dt][ks] = *(const bf16x8*)(Vt + ((size_t)bh * 64 + dt * 16 + lr) * 2048 +
                                      kt * 64 + ks * 32 + lg * 8);

    // S = K Q^T (swapped): lane holds s[nt][r] for q = lr, k = nt*16+lg*4+r
    f32x4 s[4] = {};
#pragma unroll
    for (int ks = 0; ks < 2; ++ks)
#pragma unroll
      for (int nt = 0; nt < 4; ++nt)
        s[nt] = __builtin_amdgcn_mfma_f32_16x16x32_bf16(kf[nt][ks], qf[ks], s[nt], 0, 0, 0);

    float pmax = -1e30f;
    const bool diag = (kt == qt);
#pragma unroll
    for (int nt = 0; nt < 4; ++nt)
#pragma unroll
      for (int r = 0; r < 4; ++r) {
        float v = s[nt][r] * SCALE2;
        if (diag) {
          const int kg = kt * 64 + nt * 16 + lg * 4 + r;
          v = (kg <= qg) ? v : -1e30f;
        }
        s[nt][r] = v;
        pmax = fmaxf(pmax, v);
      }

    // defer-max: rescale only when some row's max grew past THR (rare)
    if (!__all(pmax - m <= DEFER_THR)) {
      float mx = fmaxf(pmax, __shfl_xor(pmax, 16));
      mx = fmaxf(mx, __shfl_xor(mx, 32));
      const float mn = fmaxf(m, mx);
      const float alpha = fexp2(m - mn);
      m = mn;
      lp *= alpha;
#pragma unroll
      for (int r = 0; r < 4; ++r) {
        const float ar = __shfl(alpha, lg * 4 + r);
#pragma unroll
        for (int dt = 0; dt < 4; ++dt) o[dt][r] *= ar;
      }
    }

    // P = 2^(s-m): per-lane partial l, packed bf16 write (swizzled, wave-private)
#pragma unroll
    for (int nt = 0; nt < 4; ++nt) {
      const float p0 = fexp2(s[nt][0] - m), p1 = fexp2(s[nt][1] - m);
      const float p2 = fexp2(s[nt][2] - m), p3 = fexp2(s[nt][3] - m);
      lp += (p0 + p1) + (p2 + p3);
      uint2 w;
      w.x = (u32)f2bf(p0) | ((u32)f2bf(p1) << 16);
      w.y = (u32)f2bf(p2) | ((u32)f2bf(p3) << 16);
      *(uint2*)((char*)&Ps[wv][0] + lr * 128 + ((nt * 32 + lg * 8) ^ ((lr & 7) << 4))) = w;
    }

    // O += P V
    bf16x8 pf[2];
#pragma unroll
    for (int ks = 0; ks < 2; ++ks) {
      const int jp = (ks * 4 + lg) ^ (lr & 7);
      pf[ks] = *(const bf16x8*)(&Ps[wv][0] + lr * 64 + jp * 8);
    }
#pragma unroll
    for (int ks = 0; ks < 2; ++ks)
#pragma unroll
      for (int dt = 0; dt < 4; ++dt)
        o[dt] = __builtin_amdgcn_mfma_f32_16x16x32_bf16(pf[ks], vf[dt][ks], o[dt], 0, 0, 0);
  };

  // K-frag double-buffer prefetch
  bf16x8 kfA[4][2], kfB[4][2];
  loadK(kfA, 0);
  int kt = 0;
  for (; kt < qt; kt += 2) {
    loadK(kfB, kt + 1);
    compute(kfA, kt);
    if (kt + 2 <= qt) loadK(kfA, kt + 2);
    compute(kfB, kt + 1);
  }
  if (kt == qt) compute(kfA, kt);

  // epilogue: fold per-lane partial l across the 4 lg-copies, then O/l
  float lsum = lp + __shfl_xor(lp, 16);
  lsum += __shfl_xor(lsum, 32);
#pragma unroll
  for (int r = 0; r < 4; ++r) {
    const float ld = __shfl(lsum, lg * 4 + r);
    const int tok = qt * 64 + ws * 16 + lg * 4 + r;
#pragma unroll
    for (int dt = 0; dt < 4; ++dt)
      attnout[(tokbase + tok) * 1024 + h * 64 + dt * 16 + lr] = f2bf(o[dt][r] / ld);
  }
}

// ---------------------------------------------------------------------------
extern "C" void kernel_launch(void* const* d_in, const int* in_sizes, int n_in,
                              void* d_out, int out_size, void* d_ws, size_t ws_size,
                              hipStream_t stream) {
  (void)in_sizes; (void)n_in; (void)ws_size;
  const float* x_in  = (const float*)d_in[0];
  const float* ln1_g = (const float*)d_in[2];
  const float* ln1_b = (const float*)d_in[3];
  const float* Wqkv  = (const float*)d_in[4];
  const float* Wout  = (const float*)d_in[5];
  const float* bout  = (const float*)d_in[6];
  const float* ln2_g = (const float*)d_in[7];
  const float* ln2_b = (const float*)d_in[8];
  const float* W1    = (const float*)d_in[9];
  const float* b1    = (const float*)d_in[10];
  const float* W2    = (const float*)d_in[11];
  const float* b2    = (const float*)d_in[12];
  float* x = (float*)d_out;   // residual stream lives in d_out

  char* ws = (char*)d_ws;
  size_t off = 0;
  auto alloc = [&](size_t bytes) -> void* {
    void* p = ws + off;
    off += (bytes + 255) & ~(size_t)255;
    return p;
  };
  u16* WqkvT = (u16*)alloc(4ull * 3072 * 1024 * 2);
  u16* WoutT = (u16*)alloc(4ull * 1024 * 1024 * 2);
  u16* W1T   = (u16*)alloc(4ull * 8192 * 1024 * 2);
  u16* W2T   = (u16*)alloc(4ull * 1024 * 4096 * 2);
  u16* y     = (u16*)alloc(4096ull * 1024 * 2);
  u16* qkvb  = (u16*)alloc(4096ull * 3072 * 2);
  u16* Vt    = (u16*)alloc(32ull * 64 * 2048 * 2);
  u16* attn  = (u16*)alloc(4096ull * 1024 * 2);
  u16* ff    = (u16*)alloc(4096ull * 4096 * 2);

  hipMemcpyAsync(x, x_in, (size_t)out_size * 4, hipMemcpyDeviceToDevice, stream);

  const dim3 tb(32, 8);
  wtrans_kernel<<<dim3(3072 / 32, 1024 / 32, 4), tb, 0, stream>>>(Wqkv, WqkvT, 1024, 3072, 0);
  wtrans_kernel<<<dim3(1024 / 32, 1024 / 32, 4), tb, 0, stream>>>(Wout, WoutT, 1024, 1024, 0);
  wtrans_kernel<<<dim3(8192 / 32, 1024 / 32, 4), tb, 0, stream>>>(W1, W1T, 1024, 8192, 1);
  wtrans_kernel<<<dim3(1024 / 32, 4096 / 32, 4), tb, 0, stream>>>(W2, W2T, 4096, 1024, 0);

  for (int l = 0; l < 4; ++l) {
    ln_kernel<<<4096, 256, 0, stream>>>(x, ln1_g + l * 1024, ln1_b + l * 1024, y);
    gemm2<0, 128, 128, 2, 2><<<dim3(3072 / 128, 4096 / 128), 256, 0, stream>>>(
        y, WqkvT + (size_t)l * 3072 * 1024, nullptr, nullptr, qkvb, 4096, 3072, 1024);
    vtrans_kernel<<<dim3(64, 2, 32), tb, 0, stream>>>(qkvb, Vt);
    attn_kernel<<<dim3(16, 32), 512, 0, stream>>>(qkvb, Vt, attn);
    gemm2<1, 128, 128, 2, 2><<<dim3(1024 / 128, 4096 / 128), 256, 0, stream>>>(
        attn, WoutT + (size_t)l * 1024 * 1024, x, bout + l * 1024, nullptr, 4096, 1024, 1024);
    ln_kernel<<<4096, 256, 0, stream>>>(x, ln2_g + l * 1024, ln2_b + l * 1024, y);
    gemm2<2, 256, 256, 2, 4><<<dim3(8192 / 256, 4096 / 256), 512, 0, stream>>>(
        y, W1T + (size_t)l * 8192 * 1024, nullptr, b1 + l * 8192, ff, 4096, 8192, 1024);
    gemm2<1, 128, 128, 2, 2><<<dim3(1024 / 128, 4096 / 128), 256, 0, stream>>>(
        ff, W2T + (size_t)l * 1024 * 4096, x, b2 + l * 1024, nullptr, 4096, 1024, 4096);
  }
}

// Round 7
// 1432.057 us; speedup vs baseline: 1.2232x; 1.2232x over previous
//
#include <hip/hip_runtime.h>

// ---------------------------------------------------------------------------
// Transformer (B=2, N=2048, D=1024, H=16, DH=64, DEPTH=4, FF=4, GEGLU, causal)
// R7: attention = R6 structure (8-wave paired blocks, defer-max, barrier-free)
// but register-budgeted to fit 128 VGPR at 4 waves/SIMD: no K double-buffer,
// K/V fragments loaded 2-at-a-time in-loop (TLP hides L2 latency).
// GEMMs unchanged from R5 (BK=64 counted-vmcnt pipeline, T2 swizzle, T5).
// ---------------------------------------------------------------------------

typedef float f32x4 __attribute__((ext_vector_type(4)));
typedef __bf16 bf16x8 __attribute__((ext_vector_type(8)));
typedef unsigned short u16;
typedef unsigned int u32;

#define SCALE2 0.18033688011112042f   // DH^-0.5 * log2(e)
#define LN_EPS 1e-3f
#define DEFER_THR 8.0f                // log2-domain: P bounded by 2^8

__device__ __forceinline__ float fexp2(float x) { return __builtin_amdgcn_exp2f(x); }

__device__ __forceinline__ u16 f2bf(float f) {
  u32 u = __float_as_uint(f);
  u += 0x7fffu + ((u >> 16) & 1u);   // round-to-nearest-even
  return (u16)(u >> 16);
}

// async global->LDS, 16B/lane; lds base wave-uniform (HW adds lane*16)
__device__ __forceinline__ void stage16(void* lds_wave_base, const void* gsrc) {
  __builtin_amdgcn_global_load_lds((__attribute__((address_space(1))) void*)gsrc,
                                   (__attribute__((address_space(3))) void*)lds_wave_base,
                                   16, 0, 0);
}

// ---------------------------------------------------------------------------
// Weight transpose + cast: W f32 [L][K][N] -> WT bf16 [L][N][K].
// permMode=1 (W1): rows permuted so 16 a-cols / 16 gate-cols alternate.
// ---------------------------------------------------------------------------
__global__ void wtrans_kernel(const float* __restrict__ W, u16* __restrict__ WT,
                              int K, int N, int permMode) {
  __shared__ float tile[32][33];
  const int n0 = blockIdx.x * 32, k0 = blockIdx.y * 32;
  const float* Wl = W + (size_t)blockIdx.z * K * N;
  u16* WTl = WT + (size_t)blockIdx.z * K * N;
  const int tx = threadIdx.x, ty = threadIdx.y;
#pragma unroll
  for (int i = 0; i < 4; ++i)
    tile[ty + i * 8][tx] = Wl[(size_t)(k0 + ty + i * 8) * N + n0 + tx];
  __syncthreads();
#pragma unroll
  for (int i = 0; i < 4; ++i) {
    const int n = n0 + ty + i * 8;
    int orow;
    if (permMode) {
      orow = (n < 4096) ? (((n >> 4) << 5) + (n & 15))
                        : ((((n - 4096) >> 4) << 5) + 16 + (n & 15));
    } else {
      orow = n;
    }
    WTl[(size_t)orow * K + k0 + tx] = f2bf(tile[tx][ty + i * 8]);
  }
}

// V part of qkv -> per-(b,h) transposed V^T [bh][64 d][2048 tok] (bf16)
__global__ void vtrans_kernel(const u16* __restrict__ qkv, u16* __restrict__ Vt) {
  __shared__ u16 tile[32][33];
  const int t0 = blockIdx.x * 32, d0 = blockIdx.y * 32, bh = blockIdx.z;
  const int b = bh >> 4, h = bh & 15;
  const int tx = threadIdx.x, ty = threadIdx.y;
#pragma unroll
  for (int i = 0; i < 4; ++i)
    tile[ty + i * 8][tx] =
        qkv[((size_t)(b * 2048 + t0 + ty + i * 8)) * 3072 + 2048 + h * 64 + d0 + tx];
  __syncthreads();
#pragma unroll
  for (int i = 0; i < 4; ++i)
    Vt[((size_t)bh * 64 + d0 + ty + i * 8) * 2048 + t0 + tx] = tile[tx][ty + i * 8];
}

// ---------------------------------------------------------------------------
// LayerNorm: x f32 [4096][1024] -> y bf16
// ---------------------------------------------------------------------------
__global__ __launch_bounds__(256, 4)
void ln_kernel(const float* __restrict__ x, const float* __restrict__ g,
               const float* __restrict__ b, u16* __restrict__ y) {
  const int row = blockIdx.x, tid = threadIdx.x;
  const float4 v = ((const float4*)(x + (size_t)row * 1024))[tid];
  float s = v.x + v.y + v.z + v.w;
  float s2 = v.x * v.x + v.y * v.y + v.z * v.z + v.w * v.w;
#pragma unroll
  for (int off = 32; off > 0; off >>= 1) {
    s += __shfl_down(s, off);
    s2 += __shfl_down(s2, off);
  }
  __shared__ float ps[8];
  __shared__ float stats[2];
  const int wv = tid >> 6, lane = tid & 63;
  if (lane == 0) { ps[wv] = s; ps[wv + 4] = s2; }
  __syncthreads();
  if (tid == 0) {
    const float S = ps[0] + ps[1] + ps[2] + ps[3];
    const float S2 = ps[4] + ps[5] + ps[6] + ps[7];
    const float mu = S * (1.0f / 1024.0f);
    const float var = S2 * (1.0f / 1024.0f) - mu * mu;
    stats[0] = mu;
    stats[1] = rsqrtf(var + LN_EPS);
  }
  __syncthreads();
  const float mu = stats[0], rs = stats[1];
  const float4 gg = ((const float4*)g)[tid];
  const float4 bb = ((const float4*)b)[tid];
  ushort4 ov;
  ov.x = f2bf((v.x - mu) * rs * gg.x + bb.x);
  ov.y = f2bf((v.y - mu) * rs * gg.y + bb.y);
  ov.z = f2bf((v.z - mu) * rs * gg.z + bb.z);
  ov.w = f2bf((v.w - mu) * rs * gg.w + bb.w);
  ((ushort4*)(y + (size_t)row * 1024))[tid] = ov;
}

// ---------------------------------------------------------------------------
// Pipelined GEMM (R5, unchanged): BK=64, 2 LDS buffers, stage t+2 while t+1
// flies; raw s_barrier (no vmcnt drain) after stage. XOR-swizzled LDS.
// ---------------------------------------------------------------------------
template <int EPI, int BM, int BN, int WM, int WN>
__global__ __launch_bounds__(WM * WN * 64, 2)
void gemm2(const u16* __restrict__ A, const u16* __restrict__ B,
           float* __restrict__ resid, const float* __restrict__ bias,
           u16* __restrict__ out, int M, int N, int K) {
  constexpr int NTHR = WM * WN * 64;
  constexpr int MT = BM / WM / 16;
  constexpr int NT = BN / WN / 16;
  constexpr int QM = MT / 4;
  __shared__ __align__(16) u16 lds[2][(BM + BN) * 64];

  const int tid = threadIdx.x;
  const int wv = tid >> 6, lane = tid & 63;
  const int lr = lane & 15, lg = lane >> 4;
  const int wmi = wv / WN, wni = wv % WN;

  const int nwg = (int)(gridDim.x * gridDim.y);
  int id = (int)(blockIdx.y * gridDim.x + blockIdx.x);
  id = (id & 7) * (nwg >> 3) + (id >> 3);
  const int m0 = (id / (int)gridDim.x) * BM, n0 = (id % (int)gridDim.x) * BN;

  auto stage = [&](int bsel, int k0) {
    u16* dstA = &lds[bsel][0];
    u16* dstB = &lds[bsel][BM * 64];
#pragma unroll
    for (int rnd = 0; rnd < (BM * 128) / (NTHR * 16); ++rnd) {
      const int base = rnd * (NTHR * 16) + wv * 1024;
      const int off = base + lane * 16;
      const int row = off >> 7;
      const int k2 = (off & 127) ^ ((row & 7) << 4);
      stage16((char*)dstA + base, A + (size_t)(m0 + row) * K + k0 + (k2 >> 1));
    }
#pragma unroll
    for (int rnd = 0; rnd < (BN * 128) / (NTHR * 16); ++rnd) {
      const int base = rnd * (NTHR * 16) + wv * 1024;
      const int off = base + lane * 16;
      const int row = off >> 7;
      const int k2 = (off & 127) ^ ((row & 7) << 4);
      stage16((char*)dstB + base, B + (size_t)(n0 + row) * K + k0 + (k2 >> 1));
    }
  };

  f32x4 acc[MT][NT] = {};

  const int nT = K >> 6;
  stage(0, 0);
  stage(1, 64);
  asm volatile("s_waitcnt vmcnt(8)\n\ts_barrier" ::: "memory");

  for (int t = 0; t < nT; ++t) {
    const u16* As = &lds[t & 1][0];
    const u16* Bs = &lds[t & 1][BM * 64];
#pragma unroll
    for (int ks = 0; ks < 2; ++ks) {
      bf16x8 bfr[NT];
#pragma unroll
      for (int nt = 0; nt < NT; ++nt) {
        const int row = wni * (BN / WN) + nt * 16 + lr;
        bfr[nt] = *(const bf16x8*)((const char*)Bs + row * 128 +
                                   ((ks * 64 + lg * 16) ^ ((lr & 7) << 4)));
      }
#pragma unroll
      for (int qm = 0; qm < QM; ++qm) {
        bf16x8 afr[4];
#pragma unroll
        for (int i = 0; i < 4; ++i) {
          const int row = wmi * (BM / WM) + (qm * 4 + i) * 16 + lr;
          afr[i] = *(const bf16x8*)((const char*)As + row * 128 +
                                    ((ks * 64 + lg * 16) ^ ((lr & 7) << 4)));
        }
        __builtin_amdgcn_s_setprio(1);
#pragma unroll
        for (int i = 0; i < 4; ++i)
#pragma unroll
          for (int nt = 0; nt < NT; ++nt)
            acc[qm * 4 + i][nt] = __builtin_amdgcn_mfma_f32_16x16x32_bf16(
                afr[i], bfr[nt], acc[qm * 4 + i][nt], 0, 0, 0);
        __builtin_amdgcn_s_setprio(0);
      }
    }
    __syncthreads();
    if (t + 2 < nT) stage(t & 1, (t + 2) * 64);
    asm volatile("s_barrier" ::: "memory");
  }

  const int RB0 = wmi * (BM / WM), CB0 = wni * (BN / WN);
  if (EPI == 0) {
#pragma unroll
    for (int mt = 0; mt < MT; ++mt)
#pragma unroll
      for (int nt = 0; nt < NT; ++nt) {
        const int n = n0 + CB0 + nt * 16 + lr;
#pragma unroll
        for (int r = 0; r < 4; ++r) {
          const int m = m0 + RB0 + mt * 16 + lg * 4 + r;
          out[(size_t)m * N + n] = f2bf(acc[mt][nt][r]);
        }
      }
  } else if (EPI == 1) {
    float bs[NT];
#pragma unroll
    for (int nt = 0; nt < NT; ++nt) bs[nt] = bias[n0 + CB0 + nt * 16 + lr];
#pragma unroll
    for (int mt = 0; mt < MT; ++mt)
#pragma unroll
      for (int nt = 0; nt < NT; ++nt) {
        const int n = n0 + CB0 + nt * 16 + lr;
#pragma unroll
        for (int r = 0; r < 4; ++r) {
          const int m = m0 + RB0 + mt * 16 + lg * 4 + r;
          resid[(size_t)m * N + n] += acc[mt][nt][r] + bs[nt];
        }
      }
  } else {
#pragma unroll
    for (int pt = 0; pt < NT / 2; ++pt) {
      const int colA = ((n0 + CB0 + pt * 32) >> 5) * 16 + lr;
      const float ba = bias[colA];
      const float bg = bias[4096 + colA];
#pragma unroll
      for (int mt = 0; mt < MT; ++mt)
#pragma unroll
        for (int r = 0; r < 4; ++r) {
          const int m = m0 + RB0 + mt * 16 + lg * 4 + r;
          const float a = acc[mt][2 * pt][r] + ba;
          const float g = acc[mt][2 * pt + 1][r] + bg;
          const float gl = 0.5f * g * (1.0f + erff(g * 0.70710678118654752f));
          out[(size_t)m * 4096 + colA] = f2bf(a * gl);
        }
    }
  }
}

// ---------------------------------------------------------------------------
// Barrier-free causal flash attention, swapped QK^T, 8-wave paired blocks.
// Waves 0-3 -> q-tile (31-pr), waves 4-7 -> q-tile pr: uniform block weight,
// grid (16,32) all-resident at 2 blocks/CU = 4 waves/SIMD.
// Register-budgeted (<128 VGPR): no K double-buffer; K/V frags loaded
// 2-at-a-time inside the MFMA loops; defer-max common path shuffle-free.
// ---------------------------------------------------------------------------
__global__ __launch_bounds__(512, 4)
void attn_kernel(const u16* __restrict__ qkv, const u16* __restrict__ Vt,
                 u16* __restrict__ attnout) {
  __shared__ __align__(16) u16 Ps[8][16 * 64];   // wave-private P, 16 KB

  const int tid = threadIdx.x;
  const int wv = tid >> 6, lane = tid & 63;
  const int lr = lane & 15, lg = lane >> 4;
  const int pr = blockIdx.x;                     // 0..15
  const int bh = blockIdx.y;
  const int b = bh >> 4, h = bh & 15;
  const size_t tokbase = (size_t)b * 2048;
  const int qt = (wv < 4) ? (31 - pr) : pr;      // this wave's q-tile
  const int ws = wv & 3;                         // 16-row slice within tile
  const int qg = qt * 64 + ws * 16 + lr;         // this lane's global q row

  // Q fragment (B-operand of swapped QK^T)
  bf16x8 qf[2];
#pragma unroll
  for (int ks = 0; ks < 2; ++ks)
    qf[ks] = *(const bf16x8*)(qkv + (tokbase + qt * 64 + ws * 16 + lr) * 3072 +
                              h * 64 + ks * 32 + lg * 8);

  f32x4 o[4] = {};
  float m = -1e30f, lp = 0.f;    // running max (q=lr), per-lane partial l

  const u16* kbase_ptr = qkv + tokbase * 3072 + 1024 + h * 64;
  const u16* vbase_ptr = Vt + (size_t)bh * 64 * 2048;

  for (int kt = 0; kt <= qt; ++kt) {
    // S = K Q^T (swapped): lane holds s[nt][r] for q=lr, k=nt*16+lg*4+r
    f32x4 s[4] = {};
#pragma unroll
    for (int nt = 0; nt < 4; ++nt) {
      const u16* kp = kbase_ptr + (size_t)(kt * 64 + nt * 16 + lr) * 3072 + lg * 8;
      const bf16x8 k0 = *(const bf16x8*)(kp);
      const bf16x8 k1 = *(const bf16x8*)(kp + 32);
      s[nt] = __builtin_amdgcn_mfma_f32_16x16x32_bf16(k0, qf[0], s[nt], 0, 0, 0);
      s[nt] = __builtin_amdgcn_mfma_f32_16x16x32_bf16(k1, qf[1], s[nt], 0, 0, 0);
    }

    float pmax = -1e30f;
    const bool diag = (kt == qt);
#pragma unroll
    for (int nt = 0; nt < 4; ++nt)
#pragma unroll
      for (int r = 0; r < 4; ++r) {
        float v = s[nt][r] * SCALE2;
        if (diag) {
          const int kg = kt * 64 + nt * 16 + lg * 4 + r;
          v = (kg <= qg) ? v : -1e30f;
        }
        s[nt][r] = v;
        pmax = fmaxf(pmax, v);
      }

    // defer-max: rescale only when some row's max grew past THR (rare)
    if (!__all(pmax - m <= DEFER_THR)) {
      float mx = fmaxf(pmax, __shfl_xor(pmax, 16));
      mx = fmaxf(mx, __shfl_xor(mx, 32));
      const float mn = fmaxf(m, mx);
      const float alpha = fexp2(m - mn);
      m = mn;
      lp *= alpha;
#pragma unroll
      for (int r = 0; r < 4; ++r) {
        const float ar = __shfl(alpha, lg * 4 + r);
#pragma unroll
        for (int dt = 0; dt < 4; ++dt) o[dt][r] *= ar;
      }
    }

    // P = 2^(s-m): per-lane partial l, packed bf16 write (swizzled, wave-private)
#pragma unroll
    for (int nt = 0; nt < 4; ++nt) {
      const float p0 = fexp2(s[nt][0] - m), p1 = fexp2(s[nt][1] - m);
      const float p2 = fexp2(s[nt][2] - m), p3 = fexp2(s[nt][3] - m);
      lp += (p0 + p1) + (p2 + p3);
      uint2 w;
      w.x = (u32)f2bf(p0) | ((u32)f2bf(p1) << 16);
      w.y = (u32)f2bf(p2) | ((u32)f2bf(p3) << 16);
      *(uint2*)((char*)&Ps[wv][0] + lr * 128 + ((nt * 32 + lg * 8) ^ ((lr & 7) << 4))) = w;
    }

    // O += P V   (V frags loaded 2-at-a-time inside the loop)
    bf16x8 pf[2];
#pragma unroll
    for (int ks = 0; ks < 2; ++ks) {
      const int jp = (ks * 4 + lg) ^ (lr & 7);
      pf[ks] = *(const bf16x8*)(&Ps[wv][0] + lr * 64 + jp * 8);
    }
#pragma unroll
    for (int dt = 0; dt < 4; ++dt) {
      const u16* vp = vbase_ptr + (size_t)(dt * 16 + lr) * 2048 + kt * 64 + lg * 8;
      const bf16x8 v0 = *(const bf16x8*)(vp);
      const bf16x8 v1 = *(const bf16x8*)(vp + 32);
      o[dt] = __builtin_amdgcn_mfma_f32_16x16x32_bf16(pf[0], v0, o[dt], 0, 0, 0);
      o[dt] = __builtin_amdgcn_mfma_f32_16x16x32_bf16(pf[1], v1, o[dt], 0, 0, 0);
    }
  }

  // epilogue: fold per-lane partial l across the 4 lg-copies, then O/l
  float lsum = lp + __shfl_xor(lp, 16);
  lsum += __shfl_xor(lsum, 32);
#pragma unroll
  for (int r = 0; r < 4; ++r) {
    const float ld = __shfl(lsum, lg * 4 + r);
    const int tok = qt * 64 + ws * 16 + lg * 4 + r;
#pragma unroll
    for (int dt = 0; dt < 4; ++dt)
      attnout[(tokbase + tok) * 1024 + h * 64 + dt * 16 + lr] = f2bf(o[dt][r] / ld);
  }
}

// ---------------------------------------------------------------------------
extern "C" void kernel_launch(void* const* d_in, const int* in_sizes, int n_in,
                              void* d_out, int out_size, void* d_ws, size_t ws_size,
                              hipStream_t stream) {
  (void)in_sizes; (void)n_in; (void)ws_size;
  const float* x_in  = (const float*)d_in[0];
  const float* ln1_g = (const float*)d_in[2];
  const float* ln1_b = (const float*)d_in[3];
  const float* Wqkv  = (const float*)d_in[4];
  const float* Wout  = (const float*)d_in[5];
  const float* bout  = (const float*)d_in[6];
  const float* ln2_g = (const float*)d_in[7];
  const float* ln2_b = (const float*)d_in[8];
  const float* W1    = (const float*)d_in[9];
  const float* b1    = (const float*)d_in[10];
  const float* W2    = (const float*)d_in[11];
  const float* b2    = (const float*)d_in[12];
  float* x = (float*)d_out;   // residual stream lives in d_out

  char* ws = (char*)d_ws;
  size_t off = 0;
  auto alloc = [&](size_t bytes) -> void* {
    void* p = ws + off;
    off += (bytes + 255) & ~(size_t)255;
    return p;
  };
  u16* WqkvT = (u16*)alloc(4ull * 3072 * 1024 * 2);
  u16* WoutT = (u16*)alloc(4ull * 1024 * 1024 * 2);
  u16* W1T   = (u16*)alloc(4ull * 8192 * 1024 * 2);
  u16* W2T   = (u16*)alloc(4ull * 1024 * 4096 * 2);
  u16* y     = (u16*)alloc(4096ull * 1024 * 2);
  u16* qkvb  = (u16*)alloc(4096ull * 3072 * 2);
  u16* Vt    = (u16*)alloc(32ull * 64 * 2048 * 2);
  u16* attn  = (u16*)alloc(4096ull * 1024 * 2);
  u16* ff    = (u16*)alloc(4096ull * 4096 * 2);

  hipMemcpyAsync(x, x_in, (size_t)out_size * 4, hipMemcpyDeviceToDevice, stream);

  const dim3 tb(32, 8);
  wtrans_kernel<<<dim3(3072 / 32, 1024 / 32, 4), tb, 0, stream>>>(Wqkv, WqkvT, 1024, 3072, 0);
  wtrans_kernel<<<dim3(1024 / 32, 1024 / 32, 4), tb, 0, stream>>>(Wout, WoutT, 1024, 1024, 0);
  wtrans_kernel<<<dim3(8192 / 32, 1024 / 32, 4), tb, 0, stream>>>(W1, W1T, 1024, 8192, 1);
  wtrans_kernel<<<dim3(1024 / 32, 4096 / 32, 4), tb, 0, stream>>>(W2, W2T, 4096, 1024, 0);

  for (int l = 0; l < 4; ++l) {
    ln_kernel<<<4096, 256, 0, stream>>>(x, ln1_g + l * 1024, ln1_b + l * 1024, y);
    gemm2<0, 128, 128, 2, 2><<<dim3(3072 / 128, 4096 / 128), 256, 0, stream>>>(
        y, WqkvT + (size_t)l * 3072 * 1024, nullptr, nullptr, qkvb, 4096, 3072, 1024);
    vtrans_kernel<<<dim3(64, 2, 32), tb, 0, stream>>>(qkvb, Vt);
    attn_kernel<<<dim3(16, 32), 512, 0, stream>>>(qkvb, Vt, attn);
    gemm2<1, 128, 128, 2, 2><<<dim3(1024 / 128, 4096 / 128), 256, 0, stream>>>(
        attn, WoutT + (size_t)l * 1024 * 1024, x, bout + l * 1024, nullptr, 4096, 1024, 1024);
    ln_kernel<<<4096, 256, 0, stream>>>(x, ln2_g + l * 1024, ln2_b + l * 1024, y);
    gemm2<2, 256, 256, 2, 4><<<dim3(8192 / 256, 4096 / 256), 512, 0, stream>>>(
        y, W1T + (size_t)l * 8192 * 1024, nullptr, b1 + l * 8192, ff, 4096, 8192, 1024);
    gemm2<1, 128, 128, 2, 2><<<dim3(1024 / 128, 4096 / 128), 256, 0, stream>>>(
        ff, W2T + (size_t)l * 1024 * 4096, x, b2 + l * 1024, nullptr, 4096, 1024, 4096);
  }
}

// Round 8
// 1425.142 us; speedup vs baseline: 1.2292x; 1.0049x over previous
//
#include <hip/hip_runtime.h>

// ---------------------------------------------------------------------------
// Transformer (B=2, N=2048, D=1024, H=16, DH=64, DEPTH=4, FF=4, GEGLU, causal)
// R8: attention XCD-locality swizzle (each XCD owns 4 (b,h) heads entirely ->
// K/V working set fits per-XCD L2) + all K/V fragment loads issued at top of
// iteration (latency overlapped). 8-wave paired blocks, defer-max, <128 VGPR.
// GEMMs unchanged from R5 (BK=64 counted-vmcnt pipeline, T2 swizzle, T5).
// ---------------------------------------------------------------------------

typedef float f32x4 __attribute__((ext_vector_type(4)));
typedef __bf16 bf16x8 __attribute__((ext_vector_type(8)));
typedef unsigned short u16;
typedef unsigned int u32;

#define SCALE2 0.18033688011112042f   // DH^-0.5 * log2(e)
#define LN_EPS 1e-3f
#define DEFER_THR 8.0f                // log2-domain: P bounded by 2^8

__device__ __forceinline__ float fexp2(float x) { return __builtin_amdgcn_exp2f(x); }

__device__ __forceinline__ u16 f2bf(float f) {
  u32 u = __float_as_uint(f);
  u += 0x7fffu + ((u >> 16) & 1u);   // round-to-nearest-even
  return (u16)(u >> 16);
}

// async global->LDS, 16B/lane; lds base wave-uniform (HW adds lane*16)
__device__ __forceinline__ void stage16(void* lds_wave_base, const void* gsrc) {
  __builtin_amdgcn_global_load_lds((__attribute__((address_space(1))) void*)gsrc,
                                   (__attribute__((address_space(3))) void*)lds_wave_base,
                                   16, 0, 0);
}

// ---------------------------------------------------------------------------
// Weight transpose + cast: W f32 [L][K][N] -> WT bf16 [L][N][K].
// permMode=1 (W1): rows permuted so 16 a-cols / 16 gate-cols alternate.
// ---------------------------------------------------------------------------
__global__ void wtrans_kernel(const float* __restrict__ W, u16* __restrict__ WT,
                              int K, int N, int permMode) {
  __shared__ float tile[32][33];
  const int n0 = blockIdx.x * 32, k0 = blockIdx.y * 32;
  const float* Wl = W + (size_t)blockIdx.z * K * N;
  u16* WTl = WT + (size_t)blockIdx.z * K * N;
  const int tx = threadIdx.x, ty = threadIdx.y;
#pragma unroll
  for (int i = 0; i < 4; ++i)
    tile[ty + i * 8][tx] = Wl[(size_t)(k0 + ty + i * 8) * N + n0 + tx];
  __syncthreads();
#pragma unroll
  for (int i = 0; i < 4; ++i) {
    const int n = n0 + ty + i * 8;
    int orow;
    if (permMode) {
      orow = (n < 4096) ? (((n >> 4) << 5) + (n & 15))
                        : ((((n - 4096) >> 4) << 5) + 16 + (n & 15));
    } else {
      orow = n;
    }
    WTl[(size_t)orow * K + k0 + tx] = f2bf(tile[tx][ty + i * 8]);
  }
}

// V part of qkv -> per-(b,h) transposed V^T [bh][64 d][2048 tok] (bf16)
__global__ void vtrans_kernel(const u16* __restrict__ qkv, u16* __restrict__ Vt) {
  __shared__ u16 tile[32][33];
  const int t0 = blockIdx.x * 32, d0 = blockIdx.y * 32, bh = blockIdx.z;
  const int b = bh >> 4, h = bh & 15;
  const int tx = threadIdx.x, ty = threadIdx.y;
#pragma unroll
  for (int i = 0; i < 4; ++i)
    tile[ty + i * 8][tx] =
        qkv[((size_t)(b * 2048 + t0 + ty + i * 8)) * 3072 + 2048 + h * 64 + d0 + tx];
  __syncthreads();
#pragma unroll
  for (int i = 0; i < 4; ++i)
    Vt[((size_t)bh * 64 + d0 + ty + i * 8) * 2048 + t0 + tx] = tile[tx][ty + i * 8];
}

// ---------------------------------------------------------------------------
// LayerNorm: x f32 [4096][1024] -> y bf16
// ---------------------------------------------------------------------------
__global__ __launch_bounds__(256, 4)
void ln_kernel(const float* __restrict__ x, const float* __restrict__ g,
               const float* __restrict__ b, u16* __restrict__ y) {
  const int row = blockIdx.x, tid = threadIdx.x;
  const float4 v = ((const float4*)(x + (size_t)row * 1024))[tid];
  float s = v.x + v.y + v.z + v.w;
  float s2 = v.x * v.x + v.y * v.y + v.z * v.z + v.w * v.w;
#pragma unroll
  for (int off = 32; off > 0; off >>= 1) {
    s += __shfl_down(s, off);
    s2 += __shfl_down(s2, off);
  }
  __shared__ float ps[8];
  __shared__ float stats[2];
  const int wv = tid >> 6, lane = tid & 63;
  if (lane == 0) { ps[wv] = s; ps[wv + 4] = s2; }
  __syncthreads();
  if (tid == 0) {
    const float S = ps[0] + ps[1] + ps[2] + ps[3];
    const float S2 = ps[4] + ps[5] + ps[6] + ps[7];
    const float mu = S * (1.0f / 1024.0f);
    const float var = S2 * (1.0f / 1024.0f) - mu * mu;
    stats[0] = mu;
    stats[1] = rsqrtf(var + LN_EPS);
  }
  __syncthreads();
  const float mu = stats[0], rs = stats[1];
  const float4 gg = ((const float4*)g)[tid];
  const float4 bb = ((const float4*)b)[tid];
  ushort4 ov;
  ov.x = f2bf((v.x - mu) * rs * gg.x + bb.x);
  ov.y = f2bf((v.y - mu) * rs * gg.y + bb.y);
  ov.z = f2bf((v.z - mu) * rs * gg.z + bb.z);
  ov.w = f2bf((v.w - mu) * rs * gg.w + bb.w);
  ((ushort4*)(y + (size_t)row * 1024))[tid] = ov;
}

// ---------------------------------------------------------------------------
// Pipelined GEMM (R5, unchanged): BK=64, 2 LDS buffers, stage t+2 while t+1
// flies; raw s_barrier (no vmcnt drain) after stage. XOR-swizzled LDS.
// ---------------------------------------------------------------------------
template <int EPI, int BM, int BN, int WM, int WN>
__global__ __launch_bounds__(WM * WN * 64, 2)
void gemm2(const u16* __restrict__ A, const u16* __restrict__ B,
           float* __restrict__ resid, const float* __restrict__ bias,
           u16* __restrict__ out, int M, int N, int K) {
  constexpr int NTHR = WM * WN * 64;
  constexpr int MT = BM / WM / 16;
  constexpr int NT = BN / WN / 16;
  constexpr int QM = MT / 4;
  __shared__ __align__(16) u16 lds[2][(BM + BN) * 64];

  const int tid = threadIdx.x;
  const int wv = tid >> 6, lane = tid & 63;
  const int lr = lane & 15, lg = lane >> 4;
  const int wmi = wv / WN, wni = wv % WN;

  const int nwg = (int)(gridDim.x * gridDim.y);
  int id = (int)(blockIdx.y * gridDim.x + blockIdx.x);
  id = (id & 7) * (nwg >> 3) + (id >> 3);
  const int m0 = (id / (int)gridDim.x) * BM, n0 = (id % (int)gridDim.x) * BN;

  auto stage = [&](int bsel, int k0) {
    u16* dstA = &lds[bsel][0];
    u16* dstB = &lds[bsel][BM * 64];
#pragma unroll
    for (int rnd = 0; rnd < (BM * 128) / (NTHR * 16); ++rnd) {
      const int base = rnd * (NTHR * 16) + wv * 1024;
      const int off = base + lane * 16;
      const int row = off >> 7;
      const int k2 = (off & 127) ^ ((row & 7) << 4);
      stage16((char*)dstA + base, A + (size_t)(m0 + row) * K + k0 + (k2 >> 1));
    }
#pragma unroll
    for (int rnd = 0; rnd < (BN * 128) / (NTHR * 16); ++rnd) {
      const int base = rnd * (NTHR * 16) + wv * 1024;
      const int off = base + lane * 16;
      const int row = off >> 7;
      const int k2 = (off & 127) ^ ((row & 7) << 4);
      stage16((char*)dstB + base, B + (size_t)(n0 + row) * K + k0 + (k2 >> 1));
    }
  };

  f32x4 acc[MT][NT] = {};

  const int nT = K >> 6;
  stage(0, 0);
  stage(1, 64);
  asm volatile("s_waitcnt vmcnt(8)\n\ts_barrier" ::: "memory");

  for (int t = 0; t < nT; ++t) {
    const u16* As = &lds[t & 1][0];
    const u16* Bs = &lds[t & 1][BM * 64];
#pragma unroll
    for (int ks = 0; ks < 2; ++ks) {
      bf16x8 bfr[NT];
#pragma unroll
      for (int nt = 0; nt < NT; ++nt) {
        const int row = wni * (BN / WN) + nt * 16 + lr;
        bfr[nt] = *(const bf16x8*)((const char*)Bs + row * 128 +
                                   ((ks * 64 + lg * 16) ^ ((lr & 7) << 4)));
      }
#pragma unroll
      for (int qm = 0; qm < QM; ++qm) {
        bf16x8 afr[4];
#pragma unroll
        for (int i = 0; i < 4; ++i) {
          const int row = wmi * (BM / WM) + (qm * 4 + i) * 16 + lr;
          afr[i] = *(const bf16x8*)((const char*)As + row * 128 +
                                    ((ks * 64 + lg * 16) ^ ((lr & 7) << 4)));
        }
        __builtin_amdgcn_s_setprio(1);
#pragma unroll
        for (int i = 0; i < 4; ++i)
#pragma unroll
          for (int nt = 0; nt < NT; ++nt)
            acc[qm * 4 + i][nt] = __builtin_amdgcn_mfma_f32_16x16x32_bf16(
                afr[i], bfr[nt], acc[qm * 4 + i][nt], 0, 0, 0);
        __builtin_amdgcn_s_setprio(0);
      }
    }
    __syncthreads();
    if (t + 2 < nT) stage(t & 1, (t + 2) * 64);
    asm volatile("s_barrier" ::: "memory");
  }

  const int RB0 = wmi * (BM / WM), CB0 = wni * (BN / WN);
  if (EPI == 0) {
#pragma unroll
    for (int mt = 0; mt < MT; ++mt)
#pragma unroll
      for (int nt = 0; nt < NT; ++nt) {
        const int n = n0 + CB0 + nt * 16 + lr;
#pragma unroll
        for (int r = 0; r < 4; ++r) {
          const int m = m0 + RB0 + mt * 16 + lg * 4 + r;
          out[(size_t)m * N + n] = f2bf(acc[mt][nt][r]);
        }
      }
  } else if (EPI == 1) {
    float bs[NT];
#pragma unroll
    for (int nt = 0; nt < NT; ++nt) bs[nt] = bias[n0 + CB0 + nt * 16 + lr];
#pragma unroll
    for (int mt = 0; mt < MT; ++mt)
#pragma unroll
      for (int nt = 0; nt < NT; ++nt) {
        const int n = n0 + CB0 + nt * 16 + lr;
#pragma unroll
        for (int r = 0; r < 4; ++r) {
          const int m = m0 + RB0 + mt * 16 + lg * 4 + r;
          resid[(size_t)m * N + n] += acc[mt][nt][r] + bs[nt];
        }
      }
  } else {
#pragma unroll
    for (int pt = 0; pt < NT / 2; ++pt) {
      const int colA = ((n0 + CB0 + pt * 32) >> 5) * 16 + lr;
      const float ba = bias[colA];
      const float bg = bias[4096 + colA];
#pragma unroll
      for (int mt = 0; mt < MT; ++mt)
#pragma unroll
        for (int r = 0; r < 4; ++r) {
          const int m = m0 + RB0 + mt * 16 + lg * 4 + r;
          const float a = acc[mt][2 * pt][r] + ba;
          const float g = acc[mt][2 * pt + 1][r] + bg;
          const float gl = 0.5f * g * (1.0f + erff(g * 0.70710678118654752f));
          out[(size_t)m * 4096 + colA] = f2bf(a * gl);
        }
    }
  }
}

// ---------------------------------------------------------------------------
// Barrier-free causal flash attention, swapped QK^T, 8-wave paired blocks.
// XCD-locality remap: linear dispatch id -> XCD = id&7 owns bh ∈ {4x..4x+3}
// entirely, so each XCD's K/V working set (~3 MB) fits its 4 MB L2.
// All 8 K-frag + 8 V-frag loads issued at iteration top (latency overlapped).
// Defer-max softmax; per-lane partial l; wave-private swizzled P round-trip.
// ---------------------------------------------------------------------------
__global__ __launch_bounds__(512, 4)
void attn_kernel(const u16* __restrict__ qkv, const u16* __restrict__ Vt,
                 u16* __restrict__ attnout) {
  __shared__ __align__(16) u16 Ps[8][16 * 64];   // wave-private P, 16 KB

  const int tid = threadIdx.x;
  const int wv = tid >> 6, lane = tid & 63;
  const int lr = lane & 15, lg = lane >> 4;
  // XCD-locality remap (bijective on 512 blocks): XCD x gets bh = 4x..4x+3
  const int lin = (int)(blockIdx.y * gridDim.x + blockIdx.x);
  const int xcd = lin & 7, j = lin >> 3;
  const int bh = xcd * 4 + (j >> 4);
  const int pr = j & 15;
  const int b = bh >> 4, h = bh & 15;
  const size_t tokbase = (size_t)b * 2048;
  const int qt = (wv < 4) ? (31 - pr) : pr;      // this wave's q-tile
  const int ws = wv & 3;                         // 16-row slice within tile
  const int qg = qt * 64 + ws * 16 + lr;         // this lane's global q row

  // Q fragment (B-operand of swapped QK^T)
  bf16x8 qf[2];
#pragma unroll
  for (int ks = 0; ks < 2; ++ks)
    qf[ks] = *(const bf16x8*)(qkv + (tokbase + qt * 64 + ws * 16 + lr) * 3072 +
                              h * 64 + ks * 32 + lg * 8);

  f32x4 o[4] = {};
  float m = -1e30f, lp = 0.f;    // running max (q=lr), per-lane partial l

  const u16* kbase_ptr = qkv + tokbase * 3072 + 1024 + h * 64;
  const u16* vbase_ptr = Vt + (size_t)bh * 64 * 2048;

  for (int kt = 0; kt <= qt; ++kt) {
    // issue ALL K and V fragment loads up front; waits amortize together
    bf16x8 kf[4][2], vf[4][2];
#pragma unroll
    for (int nt = 0; nt < 4; ++nt) {
      const u16* kp = kbase_ptr + (size_t)(kt * 64 + nt * 16 + lr) * 3072 + lg * 8;
      kf[nt][0] = *(const bf16x8*)(kp);
      kf[nt][1] = *(const bf16x8*)(kp + 32);
    }
#pragma unroll
    for (int dt = 0; dt < 4; ++dt) {
      const u16* vp = vbase_ptr + (size_t)(dt * 16 + lr) * 2048 + kt * 64 + lg * 8;
      vf[dt][0] = *(const bf16x8*)(vp);
      vf[dt][1] = *(const bf16x8*)(vp + 32);
    }

    // S = K Q^T (swapped): lane holds s[nt][r] for q=lr, k=nt*16+lg*4+r
    f32x4 s[4] = {};
#pragma unroll
    for (int nt = 0; nt < 4; ++nt) {
      s[nt] = __builtin_amdgcn_mfma_f32_16x16x32_bf16(kf[nt][0], qf[0], s[nt], 0, 0, 0);
      s[nt] = __builtin_amdgcn_mfma_f32_16x16x32_bf16(kf[nt][1], qf[1], s[nt], 0, 0, 0);
    }

    float pmax = -1e30f;
    const bool diag = (kt == qt);
#pragma unroll
    for (int nt = 0; nt < 4; ++nt)
#pragma unroll
      for (int r = 0; r < 4; ++r) {
        float v = s[nt][r] * SCALE2;
        if (diag) {
          const int kg = kt * 64 + nt * 16 + lg * 4 + r;
          v = (kg <= qg) ? v : -1e30f;
        }
        s[nt][r] = v;
        pmax = fmaxf(pmax, v);
      }

    // defer-max: rescale only when some row's max grew past THR (rare)
    if (!__all(pmax - m <= DEFER_THR)) {
      float mx = fmaxf(pmax, __shfl_xor(pmax, 16));
      mx = fmaxf(mx, __shfl_xor(mx, 32));
      const float mn = fmaxf(m, mx);
      const float alpha = fexp2(m - mn);
      m = mn;
      lp *= alpha;
#pragma unroll
      for (int r = 0; r < 4; ++r) {
        const float ar = __shfl(alpha, lg * 4 + r);
#pragma unroll
        for (int dt = 0; dt < 4; ++dt) o[dt][r] *= ar;
      }
    }

    // P = 2^(s-m): per-lane partial l, packed bf16 write (swizzled, wave-private)
#pragma unroll
    for (int nt = 0; nt < 4; ++nt) {
      const float p0 = fexp2(s[nt][0] - m), p1 = fexp2(s[nt][1] - m);
      const float p2 = fexp2(s[nt][2] - m), p3 = fexp2(s[nt][3] - m);
      lp += (p0 + p1) + (p2 + p3);
      uint2 w;
      w.x = (u32)f2bf(p0) | ((u32)f2bf(p1) << 16);
      w.y = (u32)f2bf(p2) | ((u32)f2bf(p3) << 16);
      *(uint2*)((char*)&Ps[wv][0] + lr * 128 + ((nt * 32 + lg * 8) ^ ((lr & 7) << 4))) = w;
    }

    // O += P V
    bf16x8 pf[2];
#pragma unroll
    for (int ks = 0; ks < 2; ++ks) {
      const int jp = (ks * 4 + lg) ^ (lr & 7);
      pf[ks] = *(const bf16x8*)(&Ps[wv][0] + lr * 64 + jp * 8);
    }
#pragma unroll
    for (int dt = 0; dt < 4; ++dt) {
      o[dt] = __builtin_amdgcn_mfma_f32_16x16x32_bf16(pf[0], vf[dt][0], o[dt], 0, 0, 0);
      o[dt] = __builtin_amdgcn_mfma_f32_16x16x32_bf16(pf[1], vf[dt][1], o[dt], 0, 0, 0);
    }
  }

  // epilogue: fold per-lane partial l across the 4 lg-copies, then O/l
  float lsum = lp + __shfl_xor(lp, 16);
  lsum += __shfl_xor(lsum, 32);
#pragma unroll
  for (int r = 0; r < 4; ++r) {
    const float ld = __shfl(lsum, lg * 4 + r);
    const int tok = qt * 64 + ws * 16 + lg * 4 + r;
#pragma unroll
    for (int dt = 0; dt < 4; ++dt)
      attnout[(tokbase + tok) * 1024 + h * 64 + dt * 16 + lr] = f2bf(o[dt][r] / ld);
  }
}

// ---------------------------------------------------------------------------
extern "C" void kernel_launch(void* const* d_in, const int* in_sizes, int n_in,
                              void* d_out, int out_size, void* d_ws, size_t ws_size,
                              hipStream_t stream) {
  (void)in_sizes; (void)n_in; (void)ws_size;
  const float* x_in  = (const float*)d_in[0];
  const float* ln1_g = (const float*)d_in[2];
  const float* ln1_b = (const float*)d_in[3];
  const float* Wqkv  = (const float*)d_in[4];
  const float* Wout  = (const float*)d_in[5];
  const float* bout  = (const float*)d_in[6];
  const float* ln2_g = (const float*)d_in[7];
  const float* ln2_b = (const float*)d_in[8];
  const float* W1    = (const float*)d_in[9];
  const float* b1    = (const float*)d_in[10];
  const float* W2    = (const float*)d_in[11];
  const float* b2    = (const float*)d_in[12];
  float* x = (float*)d_out;   // residual stream lives in d_out

  char* ws = (char*)d_ws;
  size_t off = 0;
  auto alloc = [&](size_t bytes) -> void* {
    void* p = ws + off;
    off += (bytes + 255) & ~(size_t)255;
    return p;
  };
  u16* WqkvT = (u16*)alloc(4ull * 3072 * 1024 * 2);
  u16* WoutT = (u16*)alloc(4ull * 1024 * 1024 * 2);
  u16* W1T   = (u16*)alloc(4ull * 8192 * 1024 * 2);
  u16* W2T   = (u16*)alloc(4ull * 1024 * 4096 * 2);
  u16* y     = (u16*)alloc(4096ull * 1024 * 2);
  u16* qkvb  = (u16*)alloc(4096ull * 3072 * 2);
  u16* Vt    = (u16*)alloc(32ull * 64 * 2048 * 2);
  u16* attn  = (u16*)alloc(4096ull * 1024 * 2);
  u16* ff    = (u16*)alloc(4096ull * 4096 * 2);

  hipMemcpyAsync(x, x_in, (size_t)out_size * 4, hipMemcpyDeviceToDevice, stream);

  const dim3 tb(32, 8);
  wtrans_kernel<<<dim3(3072 / 32, 1024 / 32, 4), tb, 0, stream>>>(Wqkv, WqkvT, 1024, 3072, 0);
  wtrans_kernel<<<dim3(1024 / 32, 1024 / 32, 4), tb, 0, stream>>>(Wout, WoutT, 1024, 1024, 0);
  wtrans_kernel<<<dim3(8192 / 32, 1024 / 32, 4), tb, 0, stream>>>(W1, W1T, 1024, 8192, 1);
  wtrans_kernel<<<dim3(1024 / 32, 4096 / 32, 4), tb, 0, stream>>>(W2, W2T, 4096, 1024, 0);

  for (int l = 0; l < 4; ++l) {
    ln_kernel<<<4096, 256, 0, stream>>>(x, ln1_g + l * 1024, ln1_b + l * 1024, y);
    gemm2<0, 128, 128, 2, 2><<<dim3(3072 / 128, 4096 / 128), 256, 0, stream>>>(
        y, WqkvT + (size_t)l * 3072 * 1024, nullptr, nullptr, qkvb, 4096, 3072, 1024);
    vtrans_kernel<<<dim3(64, 2, 32), tb, 0, stream>>>(qkvb, Vt);
    attn_kernel<<<dim3(16, 32), 512, 0, stream>>>(qkvb, Vt, attn);
    gemm2<1, 128, 128, 2, 2><<<dim3(1024 / 128, 4096 / 128), 256, 0, stream>>>(
        attn, WoutT + (size_t)l * 1024 * 1024, x, bout + l * 1024, nullptr, 4096, 1024, 1024);
    ln_kernel<<<4096, 256, 0, stream>>>(x, ln2_g + l * 1024, ln2_b + l * 1024, y);
    gemm2<2, 256, 256, 2, 4><<<dim3(8192 / 256, 4096 / 256), 512, 0, stream>>>(
        y, W1T + (size_t)l * 8192 * 1024, nullptr, b1 + l * 8192, ff, 4096, 8192, 1024);
    gemm2<1, 128, 128, 2, 2><<<dim3(1024 / 128, 4096 / 128), 256, 0, stream>>>(
        ff, W2T + (size_t)l * 1024 * 4096, x, b2 + l * 1024, nullptr, 4096, 1024, 4096);
  }
}

// Round 9
// 1163.143 us; speedup vs baseline: 1.5061x; 1.2253x over previous
//
#include <hip/hip_runtime.h>

// ---------------------------------------------------------------------------
// Transformer (B=2, N=2048, D=1024, H=16, DH=64, DEPTH=4, FF=4, GEGLU, causal)
// R9: attention K/V staged in LDS (shared by 8 waves, 8x L1-traffic cut) with
// the R5 GEMM pipeline pattern: double-buffered tiles, stage t+2 while t+1
// flies, raw s_barrier (no vmcnt drain on hot path), XOR-swizzled rows.
// Paired panels {pr,31-pr}, XCD-pinned bh, defer-max softmax unchanged.
// GEMMs unchanged from R5.
// ---------------------------------------------------------------------------

typedef float f32x4 __attribute__((ext_vector_type(4)));
typedef __bf16 bf16x8 __attribute__((ext_vector_type(8)));
typedef unsigned short u16;
typedef unsigned int u32;

#define SCALE2 0.18033688011112042f   // DH^-0.5 * log2(e)
#define LN_EPS 1e-3f
#define DEFER_THR 8.0f                // log2-domain: P bounded by 2^8

__device__ __forceinline__ float fexp2(float x) { return __builtin_amdgcn_exp2f(x); }

__device__ __forceinline__ u16 f2bf(float f) {
  u32 u = __float_as_uint(f);
  u += 0x7fffu + ((u >> 16) & 1u);   // round-to-nearest-even
  return (u16)(u >> 16);
}

// async global->LDS, 16B/lane; lds base wave-uniform (HW adds lane*16)
__device__ __forceinline__ void stage16(void* lds_wave_base, const void* gsrc) {
  __builtin_amdgcn_global_load_lds((__attribute__((address_space(1))) void*)gsrc,
                                   (__attribute__((address_space(3))) void*)lds_wave_base,
                                   16, 0, 0);
}

// ---------------------------------------------------------------------------
// Weight transpose + cast: W f32 [L][K][N] -> WT bf16 [L][N][K].
// permMode=1 (W1): rows permuted so 16 a-cols / 16 gate-cols alternate.
// ---------------------------------------------------------------------------
__global__ void wtrans_kernel(const float* __restrict__ W, u16* __restrict__ WT,
                              int K, int N, int permMode) {
  __shared__ float tile[32][33];
  const int n0 = blockIdx.x * 32, k0 = blockIdx.y * 32;
  const float* Wl = W + (size_t)blockIdx.z * K * N;
  u16* WTl = WT + (size_t)blockIdx.z * K * N;
  const int tx = threadIdx.x, ty = threadIdx.y;
#pragma unroll
  for (int i = 0; i < 4; ++i)
    tile[ty + i * 8][tx] = Wl[(size_t)(k0 + ty + i * 8) * N + n0 + tx];
  __syncthreads();
#pragma unroll
  for (int i = 0; i < 4; ++i) {
    const int n = n0 + ty + i * 8;
    int orow;
    if (permMode) {
      orow = (n < 4096) ? (((n >> 4) << 5) + (n & 15))
                        : ((((n - 4096) >> 4) << 5) + 16 + (n & 15));
    } else {
      orow = n;
    }
    WTl[(size_t)orow * K + k0 + tx] = f2bf(tile[tx][ty + i * 8]);
  }
}

// V part of qkv -> per-(b,h) transposed V^T [bh][64 d][2048 tok] (bf16)
__global__ void vtrans_kernel(const u16* __restrict__ qkv, u16* __restrict__ Vt) {
  __shared__ u16 tile[32][33];
  const int t0 = blockIdx.x * 32, d0 = blockIdx.y * 32, bh = blockIdx.z;
  const int b = bh >> 4, h = bh & 15;
  const int tx = threadIdx.x, ty = threadIdx.y;
#pragma unroll
  for (int i = 0; i < 4; ++i)
    tile[ty + i * 8][tx] =
        qkv[((size_t)(b * 2048 + t0 + ty + i * 8)) * 3072 + 2048 + h * 64 + d0 + tx];
  __syncthreads();
#pragma unroll
  for (int i = 0; i < 4; ++i)
    Vt[((size_t)bh * 64 + d0 + ty + i * 8) * 2048 + t0 + tx] = tile[tx][ty + i * 8];
}

// ---------------------------------------------------------------------------
// LayerNorm: x f32 [4096][1024] -> y bf16
// ---------------------------------------------------------------------------
__global__ __launch_bounds__(256, 4)
void ln_kernel(const float* __restrict__ x, const float* __restrict__ g,
               const float* __restrict__ b, u16* __restrict__ y) {
  const int row = blockIdx.x, tid = threadIdx.x;
  const float4 v = ((const float4*)(x + (size_t)row * 1024))[tid];
  float s = v.x + v.y + v.z + v.w;
  float s2 = v.x * v.x + v.y * v.y + v.z * v.z + v.w * v.w;
#pragma unroll
  for (int off = 32; off > 0; off >>= 1) {
    s += __shfl_down(s, off);
    s2 += __shfl_down(s2, off);
  }
  __shared__ float ps[8];
  __shared__ float stats[2];
  const int wv = tid >> 6, lane = tid & 63;
  if (lane == 0) { ps[wv] = s; ps[wv + 4] = s2; }
  __syncthreads();
  if (tid == 0) {
    const float S = ps[0] + ps[1] + ps[2] + ps[3];
    const float S2 = ps[4] + ps[5] + ps[6] + ps[7];
    const float mu = S * (1.0f / 1024.0f);
    const float var = S2 * (1.0f / 1024.0f) - mu * mu;
    stats[0] = mu;
    stats[1] = rsqrtf(var + LN_EPS);
  }
  __syncthreads();
  const float mu = stats[0], rs = stats[1];
  const float4 gg = ((const float4*)g)[tid];
  const float4 bb = ((const float4*)b)[tid];
  ushort4 ov;
  ov.x = f2bf((v.x - mu) * rs * gg.x + bb.x);
  ov.y = f2bf((v.y - mu) * rs * gg.y + bb.y);
  ov.z = f2bf((v.z - mu) * rs * gg.z + bb.z);
  ov.w = f2bf((v.w - mu) * rs * gg.w + bb.w);
  ((ushort4*)(y + (size_t)row * 1024))[tid] = ov;
}

// ---------------------------------------------------------------------------
// Pipelined GEMM (R5, unchanged): BK=64, 2 LDS buffers, stage t+2 while t+1
// flies; raw s_barrier (no vmcnt drain) after stage. XOR-swizzled LDS.
// ---------------------------------------------------------------------------
template <int EPI, int BM, int BN, int WM, int WN>
__global__ __launch_bounds__(WM * WN * 64, 2)
void gemm2(const u16* __restrict__ A, const u16* __restrict__ B,
           float* __restrict__ resid, const float* __restrict__ bias,
           u16* __restrict__ out, int M, int N, int K) {
  constexpr int NTHR = WM * WN * 64;
  constexpr int MT = BM / WM / 16;
  constexpr int NT = BN / WN / 16;
  constexpr int QM = MT / 4;
  __shared__ __align__(16) u16 lds[2][(BM + BN) * 64];

  const int tid = threadIdx.x;
  const int wv = tid >> 6, lane = tid & 63;
  const int lr = lane & 15, lg = lane >> 4;
  const int wmi = wv / WN, wni = wv % WN;

  const int nwg = (int)(gridDim.x * gridDim.y);
  int id = (int)(blockIdx.y * gridDim.x + blockIdx.x);
  id = (id & 7) * (nwg >> 3) + (id >> 3);
  const int m0 = (id / (int)gridDim.x) * BM, n0 = (id % (int)gridDim.x) * BN;

  auto stage = [&](int bsel, int k0) {
    u16* dstA = &lds[bsel][0];
    u16* dstB = &lds[bsel][BM * 64];
#pragma unroll
    for (int rnd = 0; rnd < (BM * 128) / (NTHR * 16); ++rnd) {
      const int base = rnd * (NTHR * 16) + wv * 1024;
      const int off = base + lane * 16;
      const int row = off >> 7;
      const int k2 = (off & 127) ^ ((row & 7) << 4);
      stage16((char*)dstA + base, A + (size_t)(m0 + row) * K + k0 + (k2 >> 1));
    }
#pragma unroll
    for (int rnd = 0; rnd < (BN * 128) / (NTHR * 16); ++rnd) {
      const int base = rnd * (NTHR * 16) + wv * 1024;
      const int off = base + lane * 16;
      const int row = off >> 7;
      const int k2 = (off & 127) ^ ((row & 7) << 4);
      stage16((char*)dstB + base, B + (size_t)(n0 + row) * K + k0 + (k2 >> 1));
    }
  };

  f32x4 acc[MT][NT] = {};

  const int nT = K >> 6;
  stage(0, 0);
  stage(1, 64);
  asm volatile("s_waitcnt vmcnt(8)\n\ts_barrier" ::: "memory");

  for (int t = 0; t < nT; ++t) {
    const u16* As = &lds[t & 1][0];
    const u16* Bs = &lds[t & 1][BM * 64];
#pragma unroll
    for (int ks = 0; ks < 2; ++ks) {
      bf16x8 bfr[NT];
#pragma unroll
      for (int nt = 0; nt < NT; ++nt) {
        const int row = wni * (BN / WN) + nt * 16 + lr;
        bfr[nt] = *(const bf16x8*)((const char*)Bs + row * 128 +
                                   ((ks * 64 + lg * 16) ^ ((lr & 7) << 4)));
      }
#pragma unroll
      for (int qm = 0; qm < QM; ++qm) {
        bf16x8 afr[4];
#pragma unroll
        for (int i = 0; i < 4; ++i) {
          const int row = wmi * (BM / WM) + (qm * 4 + i) * 16 + lr;
          afr[i] = *(const bf16x8*)((const char*)As + row * 128 +
                                    ((ks * 64 + lg * 16) ^ ((lr & 7) << 4)));
        }
        __builtin_amdgcn_s_setprio(1);
#pragma unroll
        for (int i = 0; i < 4; ++i)
#pragma unroll
          for (int nt = 0; nt < NT; ++nt)
            acc[qm * 4 + i][nt] = __builtin_amdgcn_mfma_f32_16x16x32_bf16(
                afr[i], bfr[nt], acc[qm * 4 + i][nt], 0, 0, 0);
        __builtin_amdgcn_s_setprio(0);
      }
    }
    __syncthreads();
    if (t + 2 < nT) stage(t & 1, (t + 2) * 64);
    asm volatile("s_barrier" ::: "memory");
  }

  const int RB0 = wmi * (BM / WM), CB0 = wni * (BN / WN);
  if (EPI == 0) {
#pragma unroll
    for (int mt = 0; mt < MT; ++mt)
#pragma unroll
      for (int nt = 0; nt < NT; ++nt) {
        const int n = n0 + CB0 + nt * 16 + lr;
#pragma unroll
        for (int r = 0; r < 4; ++r) {
          const int m = m0 + RB0 + mt * 16 + lg * 4 + r;
          out[(size_t)m * N + n] = f2bf(acc[mt][nt][r]);
        }
      }
  } else if (EPI == 1) {
    float bs[NT];
#pragma unroll
    for (int nt = 0; nt < NT; ++nt) bs[nt] = bias[n0 + CB0 + nt * 16 + lr];
#pragma unroll
    for (int mt = 0; mt < MT; ++mt)
#pragma unroll
      for (int nt = 0; nt < NT; ++nt) {
        const int n = n0 + CB0 + nt * 16 + lr;
#pragma unroll
        for (int r = 0; r < 4; ++r) {
          const int m = m0 + RB0 + mt * 16 + lg * 4 + r;
          resid[(size_t)m * N + n] += acc[mt][nt][r] + bs[nt];
        }
      }
  } else {
#pragma unroll
    for (int pt = 0; pt < NT / 2; ++pt) {
      const int colA = ((n0 + CB0 + pt * 32) >> 5) * 16 + lr;
      const float ba = bias[colA];
      const float bg = bias[4096 + colA];
#pragma unroll
      for (int mt = 0; mt < MT; ++mt)
#pragma unroll
        for (int r = 0; r < 4; ++r) {
          const int m = m0 + RB0 + mt * 16 + lg * 4 + r;
          const float a = acc[mt][2 * pt][r] + ba;
          const float g = acc[mt][2 * pt + 1][r] + bg;
          const float gl = 0.5f * g * (1.0f + erff(g * 0.70710678118654752f));
          out[(size_t)m * 4096 + colA] = f2bf(a * gl);
        }
    }
  }
}

// ---------------------------------------------------------------------------
// Causal flash attention, LDS-staged K/V shared by 8 waves.
// Block = paired q-panels {pr, 31-pr}: waves 0-3 -> panel 31-pr, waves 4-7 ->
// panel pr. K/V tiles (64 tok x 64 d, XOR-swizzled rows) double-buffered in
// LDS via global_load_lds; stage t+2 while t+1 flies (R5 pipeline pattern).
// XCD-pinned bh (L2-resident), swapped QK^T, defer-max, per-lane partial l.
// ---------------------------------------------------------------------------
__global__ __launch_bounds__(512, 4)
void attn_kernel(const u16* __restrict__ qkv, const u16* __restrict__ Vt,
                 u16* __restrict__ attnout) {
  __shared__ __align__(16) u16 KV[2][2][64 * 64];   // [buf][K/V][row*64+col] 32 KB
  __shared__ __align__(16) u16 Ps[8][16 * 64];      // wave-private P, 16 KB

  const int tid = threadIdx.x;
  const int wv = tid >> 6, lane = tid & 63;
  const int lr = lane & 15, lg = lane >> 4;
  // XCD-locality remap (bijective on 512 blocks): XCD x gets bh = 4x..4x+3
  const int lin = (int)(blockIdx.y * gridDim.x + blockIdx.x);
  const int xcd = lin & 7, j = lin >> 3;
  const int bh = xcd * 4 + (j >> 4);
  const int pr = j & 15;
  const int b = bh >> 4, h = bh & 15;
  const size_t tokbase = (size_t)b * 2048;
  const int qhi = 31 - pr;                       // block loop bound (uniform)
  const int qt = (wv < 4) ? qhi : pr;            // this wave's q-panel
  const int ws = wv & 3;                         // 16-row slice within panel
  const int qg = qt * 64 + ws * 16 + lr;         // this lane's global q row

  // Q fragment (B-operand of swapped QK^T)
  bf16x8 qf[2];
#pragma unroll
  for (int ks = 0; ks < 2; ++ks)
    qf[ks] = *(const bf16x8*)(qkv + (tokbase + qt * 64 + ws * 16 + lr) * 3072 +
                              h * 64 + ks * 32 + lg * 8);

  f32x4 o[4] = {};
  float m = -1e30f, lp = 0.f;    // running max (q=lr), per-lane partial l

  const u16* kg_base = qkv + tokbase * 3072 + 1024 + h * 64;
  const u16* vg_base = Vt + (size_t)bh * 64 * 2048;

  // stage K+V tile kt2 into buffer bsel: 512 thr x 16B covers each 8 KB tile.
  // LDS dest linear (wave-uniform base); source col pre-XOR-swizzled (rule 21).
  const int soff = tid * 16;
  const int srow = soff >> 7;
  const int scol = (soff & 127) ^ ((srow & 7) << 4);
  auto stage = [&](int bsel, int kt2) {
    stage16((char*)&KV[bsel][0][0] + wv * 1024,
            kg_base + (size_t)(kt2 * 64 + srow) * 3072 + (scol >> 1));
    stage16((char*)&KV[bsel][1][0] + wv * 1024,
            vg_base + (size_t)srow * 2048 + kt2 * 64 + (scol >> 1));
  };

  stage(0, 0);
  stage(1, 1);   // qhi >= 16 always, so tile 1 exists
  asm volatile("s_waitcnt vmcnt(2)\n\ts_barrier" ::: "memory");

  for (int kt = 0; kt <= qhi; ++kt) {
    if (kt <= qt) {
      const char* Ks = (const char*)&KV[kt & 1][0][0];
      const char* Vs = (const char*)&KV[kt & 1][1][0];

      // S = K Q^T (swapped): lane holds s[nt][r] for q=lr, k=nt*16+lg*4+r
      f32x4 s[4] = {};
#pragma unroll
      for (int ks = 0; ks < 2; ++ks)
#pragma unroll
        for (int nt = 0; nt < 4; ++nt) {
          const int row = nt * 16 + lr;
          const bf16x8 kf = *(const bf16x8*)(Ks + row * 128 +
                                             ((ks * 64 + lg * 16) ^ ((lr & 7) << 4)));
          s[nt] = __builtin_amdgcn_mfma_f32_16x16x32_bf16(kf, qf[ks], s[nt], 0, 0, 0);
        }

      float pmax = -1e30f;
      const bool diag = (kt == qt);
#pragma unroll
      for (int nt = 0; nt < 4; ++nt)
#pragma unroll
        for (int r = 0; r < 4; ++r) {
          float v = s[nt][r] * SCALE2;
          if (diag) {
            const int kg = kt * 64 + nt * 16 + lg * 4 + r;
            v = (kg <= qg) ? v : -1e30f;
          }
          s[nt][r] = v;
          pmax = fmaxf(pmax, v);
        }

      // defer-max: rescale only when some row's max grew past THR (rare)
      if (!__all(pmax - m <= DEFER_THR)) {
        float mx = fmaxf(pmax, __shfl_xor(pmax, 16));
        mx = fmaxf(mx, __shfl_xor(mx, 32));
        const float mn = fmaxf(m, mx);
        const float alpha = fexp2(m - mn);
        m = mn;
        lp *= alpha;
#pragma unroll
        for (int r = 0; r < 4; ++r) {
          const float ar = __shfl(alpha, lg * 4 + r);
#pragma unroll
          for (int dt = 0; dt < 4; ++dt) o[dt][r] *= ar;
        }
      }

      // P = 2^(s-m): per-lane partial l, packed bf16 write (swizzled)
#pragma unroll
      for (int nt = 0; nt < 4; ++nt) {
        const float p0 = fexp2(s[nt][0] - m), p1 = fexp2(s[nt][1] - m);
        const float p2 = fexp2(s[nt][2] - m), p3 = fexp2(s[nt][3] - m);
        lp += (p0 + p1) + (p2 + p3);
        uint2 w;
        w.x = (u32)f2bf(p0) | ((u32)f2bf(p1) << 16);
        w.y = (u32)f2bf(p2) | ((u32)f2bf(p3) << 16);
        *(uint2*)((char*)&Ps[wv][0] + lr * 128 + ((nt * 32 + lg * 8) ^ ((lr & 7) << 4))) = w;
      }

      // O += P V
      bf16x8 pf[2];
#pragma unroll
      for (int ks = 0; ks < 2; ++ks) {
        const int jp = (ks * 4 + lg) ^ (lr & 7);
        pf[ks] = *(const bf16x8*)(&Ps[wv][0] + lr * 64 + jp * 8);
      }
#pragma unroll
      for (int ks = 0; ks < 2; ++ks)
#pragma unroll
        for (int dt = 0; dt < 4; ++dt) {
          const int row = dt * 16 + lr;
          const bf16x8 vf = *(const bf16x8*)(Vs + row * 128 +
                                             ((ks * 64 + lg * 16) ^ ((lr & 7) << 4)));
          o[dt] = __builtin_amdgcn_mfma_f32_16x16x32_bf16(pf[ks], vf, o[dt], 0, 0, 0);
        }
    }

    __syncthreads();                       // frees buf[kt&1]; drains kt+1 loads
    if (kt + 2 <= qhi) stage(kt & 1, kt + 2);
    asm volatile("s_barrier" ::: "memory");   // kt+2 loads stay in flight
  }

  // epilogue: fold per-lane partial l across the 4 lg-copies, then O/l
  float lsum = lp + __shfl_xor(lp, 16);
  lsum += __shfl_xor(lsum, 32);
#pragma unroll
  for (int r = 0; r < 4; ++r) {
    const float ld = __shfl(lsum, lg * 4 + r);
    const int tok = qt * 64 + ws * 16 + lg * 4 + r;
#pragma unroll
    for (int dt = 0; dt < 4; ++dt)
      attnout[(tokbase + tok) * 1024 + h * 64 + dt * 16 + lr] = f2bf(o[dt][r] / ld);
  }
}

// ---------------------------------------------------------------------------
extern "C" void kernel_launch(void* const* d_in, const int* in_sizes, int n_in,
                              void* d_out, int out_size, void* d_ws, size_t ws_size,
                              hipStream_t stream) {
  (void)in_sizes; (void)n_in; (void)ws_size;
  const float* x_in  = (const float*)d_in[0];
  const float* ln1_g = (const float*)d_in[2];
  const float* ln1_b = (const float*)d_in[3];
  const float* Wqkv  = (const float*)d_in[4];
  const float* Wout  = (const float*)d_in[5];
  const float* bout  = (const float*)d_in[6];
  const float* ln2_g = (const float*)d_in[7];
  const float* ln2_b = (const float*)d_in[8];
  const float* W1    = (const float*)d_in[9];
  const float* b1    = (const float*)d_in[10];
  const float* W2    = (const float*)d_in[11];
  const float* b2    = (const float*)d_in[12];
  float* x = (float*)d_out;   // residual stream lives in d_out

  char* ws = (char*)d_ws;
  size_t off = 0;
  auto alloc = [&](size_t bytes) -> void* {
    void* p = ws + off;
    off += (bytes + 255) & ~(size_t)255;
    return p;
  };
  u16* WqkvT = (u16*)alloc(4ull * 3072 * 1024 * 2);
  u16* WoutT = (u16*)alloc(4ull * 1024 * 1024 * 2);
  u16* W1T   = (u16*)alloc(4ull * 8192 * 1024 * 2);
  u16* W2T   = (u16*)alloc(4ull * 1024 * 4096 * 2);
  u16* y     = (u16*)alloc(4096ull * 1024 * 2);
  u16* qkvb  = (u16*)alloc(4096ull * 3072 * 2);
  u16* Vt    = (u16*)alloc(32ull * 64 * 2048 * 2);
  u16* attn  = (u16*)alloc(4096ull * 1024 * 2);
  u16* ff    = (u16*)alloc(4096ull * 4096 * 2);

  hipMemcpyAsync(x, x_in, (size_t)out_size * 4, hipMemcpyDeviceToDevice, stream);

  const dim3 tb(32, 8);
  wtrans_kernel<<<dim3(3072 / 32, 1024 / 32, 4), tb, 0, stream>>>(Wqkv, WqkvT, 1024, 3072, 0);
  wtrans_kernel<<<dim3(1024 / 32, 1024 / 32, 4), tb, 0, stream>>>(Wout, WoutT, 1024, 1024, 0);
  wtrans_kernel<<<dim3(8192 / 32, 1024 / 32, 4), tb, 0, stream>>>(W1, W1T, 1024, 8192, 1);
  wtrans_kernel<<<dim3(1024 / 32, 4096 / 32, 4), tb, 0, stream>>>(W2, W2T, 4096, 1024, 0);

  for (int l = 0; l < 4; ++l) {
    ln_kernel<<<4096, 256, 0, stream>>>(x, ln1_g + l * 1024, ln1_b + l * 1024, y);
    gemm2<0, 128, 128, 2, 2><<<dim3(3072 / 128, 4096 / 128), 256, 0, stream>>>(
        y, WqkvT + (size_t)l * 3072 * 1024, nullptr, nullptr, qkvb, 4096, 3072, 1024);
    vtrans_kernel<<<dim3(64, 2, 32), tb, 0, stream>>>(qkvb, Vt);
    attn_kernel<<<dim3(16, 32), 512, 0, stream>>>(qkvb, Vt, attn);
    gemm2<1, 128, 128, 2, 2><<<dim3(1024 / 128, 4096 / 128), 256, 0, stream>>>(
        attn, WoutT + (size_t)l * 1024 * 1024, x, bout + l * 1024, nullptr, 4096, 1024, 1024);
    ln_kernel<<<4096, 256, 0, stream>>>(x, ln2_g + l * 1024, ln2_b + l * 1024, y);
    gemm2<2, 256, 256, 2, 4><<<dim3(8192 / 256, 4096 / 256), 512, 0, stream>>>(
        y, W1T + (size_t)l * 8192 * 1024, nullptr, b1 + l * 8192, ff, 4096, 8192, 1024);
    gemm2<1, 128, 128, 2, 2><<<dim3(1024 / 128, 4096 / 128), 256, 0, stream>>>(
        ff, W2T + (size_t)l * 1024 * 4096, x, b2 + l * 1024, nullptr, 4096, 1024, 4096);
  }
}

// Round 10
// 1161.893 us; speedup vs baseline: 1.5077x; 1.0011x over previous
//
#include <hip/hip_runtime.h>

// ---------------------------------------------------------------------------
// Transformer (B=2, N=2048, D=1024, H=16, DH=64, DEPTH=4, FF=4, GEGLU, causal)
// R10: GEMM schedule v3 — frag preload to registers, early LDS-free barrier
// (lgkmcnt(0)+s_barrier right after ds_reads), stage t+2 into freed buffer,
// pure-register MFMA cluster under setprio, counted vmcnt(8) tile joins
// (never 0 on hot path). Attention/LN/transposes unchanged from R9.
// ---------------------------------------------------------------------------

typedef float f32x4 __attribute__((ext_vector_type(4)));
typedef __bf16 bf16x8 __attribute__((ext_vector_type(8)));
typedef unsigned short u16;
typedef unsigned int u32;

#define SCALE2 0.18033688011112042f   // DH^-0.5 * log2(e)
#define LN_EPS 1e-3f
#define DEFER_THR 8.0f                // log2-domain: P bounded by 2^8

__device__ __forceinline__ float fexp2(float x) { return __builtin_amdgcn_exp2f(x); }

__device__ __forceinline__ u16 f2bf(float f) {
  u32 u = __float_as_uint(f);
  u += 0x7fffu + ((u >> 16) & 1u);   // round-to-nearest-even
  return (u16)(u >> 16);
}

// async global->LDS, 16B/lane; lds base wave-uniform (HW adds lane*16)
__device__ __forceinline__ void stage16(void* lds_wave_base, const void* gsrc) {
  __builtin_amdgcn_global_load_lds((__attribute__((address_space(1))) void*)gsrc,
                                   (__attribute__((address_space(3))) void*)lds_wave_base,
                                   16, 0, 0);
}

// ---------------------------------------------------------------------------
// Weight transpose + cast: W f32 [L][K][N] -> WT bf16 [L][N][K].
// permMode=1 (W1): rows permuted so 16 a-cols / 16 gate-cols alternate.
// ---------------------------------------------------------------------------
__global__ void wtrans_kernel(const float* __restrict__ W, u16* __restrict__ WT,
                              int K, int N, int permMode) {
  __shared__ float tile[32][33];
  const int n0 = blockIdx.x * 32, k0 = blockIdx.y * 32;
  const float* Wl = W + (size_t)blockIdx.z * K * N;
  u16* WTl = WT + (size_t)blockIdx.z * K * N;
  const int tx = threadIdx.x, ty = threadIdx.y;
#pragma unroll
  for (int i = 0; i < 4; ++i)
    tile[ty + i * 8][tx] = Wl[(size_t)(k0 + ty + i * 8) * N + n0 + tx];
  __syncthreads();
#pragma unroll
  for (int i = 0; i < 4; ++i) {
    const int n = n0 + ty + i * 8;
    int orow;
    if (permMode) {
      orow = (n < 4096) ? (((n >> 4) << 5) + (n & 15))
                        : ((((n - 4096) >> 4) << 5) + 16 + (n & 15));
    } else {
      orow = n;
    }
    WTl[(size_t)orow * K + k0 + tx] = f2bf(tile[tx][ty + i * 8]);
  }
}

// V part of qkv -> per-(b,h) transposed V^T [bh][64 d][2048 tok] (bf16)
__global__ void vtrans_kernel(const u16* __restrict__ qkv, u16* __restrict__ Vt) {
  __shared__ u16 tile[32][33];
  const int t0 = blockIdx.x * 32, d0 = blockIdx.y * 32, bh = blockIdx.z;
  const int b = bh >> 4, h = bh & 15;
  const int tx = threadIdx.x, ty = threadIdx.y;
#pragma unroll
  for (int i = 0; i < 4; ++i)
    tile[ty + i * 8][tx] =
        qkv[((size_t)(b * 2048 + t0 + ty + i * 8)) * 3072 + 2048 + h * 64 + d0 + tx];
  __syncthreads();
#pragma unroll
  for (int i = 0; i < 4; ++i)
    Vt[((size_t)bh * 64 + d0 + ty + i * 8) * 2048 + t0 + tx] = tile[tx][ty + i * 8];
}

// ---------------------------------------------------------------------------
// LayerNorm: x f32 [4096][1024] -> y bf16
// ---------------------------------------------------------------------------
__global__ __launch_bounds__(256, 4)
void ln_kernel(const float* __restrict__ x, const float* __restrict__ g,
               const float* __restrict__ b, u16* __restrict__ y) {
  const int row = blockIdx.x, tid = threadIdx.x;
  const float4 v = ((const float4*)(x + (size_t)row * 1024))[tid];
  float s = v.x + v.y + v.z + v.w;
  float s2 = v.x * v.x + v.y * v.y + v.z * v.z + v.w * v.w;
#pragma unroll
  for (int off = 32; off > 0; off >>= 1) {
    s += __shfl_down(s, off);
    s2 += __shfl_down(s2, off);
  }
  __shared__ float ps[8];
  __shared__ float stats[2];
  const int wv = tid >> 6, lane = tid & 63;
  if (lane == 0) { ps[wv] = s; ps[wv + 4] = s2; }
  __syncthreads();
  if (tid == 0) {
    const float S = ps[0] + ps[1] + ps[2] + ps[3];
    const float S2 = ps[4] + ps[5] + ps[6] + ps[7];
    const float mu = S * (1.0f / 1024.0f);
    const float var = S2 * (1.0f / 1024.0f) - mu * mu;
    stats[0] = mu;
    stats[1] = rsqrtf(var + LN_EPS);
  }
  __syncthreads();
  const float mu = stats[0], rs = stats[1];
  const float4 gg = ((const float4*)g)[tid];
  const float4 bb = ((const float4*)b)[tid];
  ushort4 ov;
  ov.x = f2bf((v.x - mu) * rs * gg.x + bb.x);
  ov.y = f2bf((v.y - mu) * rs * gg.y + bb.y);
  ov.z = f2bf((v.z - mu) * rs * gg.z + bb.z);
  ov.w = f2bf((v.w - mu) * rs * gg.w + bb.w);
  ((ushort4*)(y + (size_t)row * 1024))[tid] = ov;
}

// ---------------------------------------------------------------------------
// GEMM v3: C[M,N] = A[M,K] * B^T[N,K], bf16, fp32 acc, BK=64, 2 LDS buffers.
// Per tile t (buf c=t&1):
//   1. ds_read ALL wave frags (A,B; both ks halves) into registers
//   2. lgkmcnt(0) + s_barrier  -> buf c LDS is FREE (regs hold the data)
//   3. stage tile t+2 into buf c (8 global_load_lds/wave, fly during MFMA)
//   4. setprio(1); 2*MT*NT MFMA from registers only; setprio(0)
//   5. join tile t+1: s_waitcnt vmcnt(8) + s_barrier (counted — t+2 stays
//      in flight across the barrier; vmcnt(0) only at the tail)
// ---------------------------------------------------------------------------
template <int EPI, int BM, int BN, int WM, int WN>
__global__ __launch_bounds__(WM * WN * 64, 2)
void gemm3(const u16* __restrict__ A, const u16* __restrict__ B,
           float* __restrict__ resid, const float* __restrict__ bias,
           u16* __restrict__ out, int M, int N, int K) {
  constexpr int NTHR = WM * WN * 64;
  constexpr int MT = BM / WM / 16;
  constexpr int NT = BN / WN / 16;
  __shared__ __align__(16) u16 lds[2][(BM + BN) * 64];

  const int tid = threadIdx.x;
  const int wv = tid >> 6, lane = tid & 63;
  const int lr = lane & 15, lg = lane >> 4;
  const int wmi = wv / WN, wni = wv % WN;
  const int RB0 = wmi * (BM / WM), CB0 = wni * (BN / WN);

  const int nwg = (int)(gridDim.x * gridDim.y);
  int id = (int)(blockIdx.y * gridDim.x + blockIdx.x);
  id = (id & 7) * (nwg >> 3) + (id >> 3);
  const int m0 = (id / (int)gridDim.x) * BM, n0 = (id % (int)gridDim.x) * BN;

  auto stage = [&](int bsel, int k0) {
    u16* dstA = &lds[bsel][0];
    u16* dstB = &lds[bsel][BM * 64];
#pragma unroll
    for (int rnd = 0; rnd < (BM * 128) / (NTHR * 16); ++rnd) {
      const int base = rnd * (NTHR * 16) + wv * 1024;
      const int off = base + lane * 16;
      const int row = off >> 7;
      const int k2 = (off & 127) ^ ((row & 7) << 4);
      stage16((char*)dstA + base, A + (size_t)(m0 + row) * K + k0 + (k2 >> 1));
    }
#pragma unroll
    for (int rnd = 0; rnd < (BN * 128) / (NTHR * 16); ++rnd) {
      const int base = rnd * (NTHR * 16) + wv * 1024;
      const int off = base + lane * 16;
      const int row = off >> 7;
      const int k2 = (off & 127) ^ ((row & 7) << 4);
      stage16((char*)dstB + base, B + (size_t)(n0 + row) * K + k0 + (k2 >> 1));
    }
  };

  f32x4 acc[MT][NT] = {};

  const int nT = K >> 6;
  stage(0, 0);
  stage(1, 64);
  // join tile 0: 16 outstanding, oldest 8 (tile 0) must land
  asm volatile("s_waitcnt vmcnt(8)\n\ts_barrier" ::: "memory");

  for (int t = 0; t < nT; ++t) {
    const char* As = (const char*)&lds[t & 1][0];
    const char* Bs = (const char*)&lds[t & 1][BM * 64];

    // 1. preload all fragments into registers
    bf16x8 afr[2][MT], bfr[2][NT];
#pragma unroll
    for (int ks = 0; ks < 2; ++ks) {
#pragma unroll
      for (int nt = 0; nt < NT; ++nt) {
        const int row = CB0 + nt * 16 + lr;
        bfr[ks][nt] = *(const bf16x8*)(Bs + row * 128 +
                                       ((ks * 64 + lg * 16) ^ ((lr & 7) << 4)));
      }
#pragma unroll
      for (int mt = 0; mt < MT; ++mt) {
        const int row = RB0 + mt * 16 + lr;
        afr[ks][mt] = *(const bf16x8*)(As + row * 128 +
                                       ((ks * 64 + lg * 16) ^ ((lr & 7) << 4)));
      }
    }
    // 2. all waves' reads done -> LDS buffer free for overwrite
    __builtin_amdgcn_sched_barrier(0);
    asm volatile("s_waitcnt lgkmcnt(0)\n\ts_barrier" ::: "memory");
    __builtin_amdgcn_sched_barrier(0);
    // 3. stage t+2 into the freed buffer; flies during the MFMA cluster
    if (t + 2 < nT) stage(t & 1, (t + 2) * 64);
    // 4. pure-register MFMA cluster
    __builtin_amdgcn_s_setprio(1);
#pragma unroll
    for (int ks = 0; ks < 2; ++ks)
#pragma unroll
      for (int mt = 0; mt < MT; ++mt)
#pragma unroll
        for (int nt = 0; nt < NT; ++nt)
          acc[mt][nt] = __builtin_amdgcn_mfma_f32_16x16x32_bf16(
              afr[ks][mt], bfr[ks][nt], acc[mt][nt], 0, 0, 0);
    __builtin_amdgcn_s_setprio(0);
    // 5. counted join for tile t+1
    if (t + 1 < nT) {
      if (t + 2 < nT)
        asm volatile("s_waitcnt vmcnt(8)\n\ts_barrier" ::: "memory");
      else
        asm volatile("s_waitcnt vmcnt(0)\n\ts_barrier" ::: "memory");
    }
  }

  // C/D: m = m0 + RB0 + mt*16 + lg*4 + r ; n = n0 + CB0 + nt*16 + lr
  if (EPI == 0) {
#pragma unroll
    for (int mt = 0; mt < MT; ++mt)
#pragma unroll
      for (int nt = 0; nt < NT; ++nt) {
        const int n = n0 + CB0 + nt * 16 + lr;
#pragma unroll
        for (int r = 0; r < 4; ++r) {
          const int m = m0 + RB0 + mt * 16 + lg * 4 + r;
          out[(size_t)m * N + n] = f2bf(acc[mt][nt][r]);
        }
      }
  } else if (EPI == 1) {
    float bs[NT];
#pragma unroll
    for (int nt = 0; nt < NT; ++nt) bs[nt] = bias[n0 + CB0 + nt * 16 + lr];
#pragma unroll
    for (int mt = 0; mt < MT; ++mt)
#pragma unroll
      for (int nt = 0; nt < NT; ++nt) {
        const int n = n0 + CB0 + nt * 16 + lr;
#pragma unroll
        for (int r = 0; r < 4; ++r) {
          const int m = m0 + RB0 + mt * 16 + lg * 4 + r;
          resid[(size_t)m * N + n] += acc[mt][nt][r] + bs[nt];
        }
      }
  } else {
#pragma unroll
    for (int pt = 0; pt < NT / 2; ++pt) {
      const int colA = ((n0 + CB0 + pt * 32) >> 5) * 16 + lr;
      const float ba = bias[colA];
      const float bg = bias[4096 + colA];
#pragma unroll
      for (int mt = 0; mt < MT; ++mt)
#pragma unroll
        for (int r = 0; r < 4; ++r) {
          const int m = m0 + RB0 + mt * 16 + lg * 4 + r;
          const float a = acc[mt][2 * pt][r] + ba;
          const float g = acc[mt][2 * pt + 1][r] + bg;
          const float gl = 0.5f * g * (1.0f + erff(g * 0.70710678118654752f));
          out[(size_t)m * 4096 + colA] = f2bf(a * gl);
        }
    }
  }
}

// ---------------------------------------------------------------------------
// Causal flash attention (R9, unchanged): LDS-staged K/V shared by 8 waves,
// double-buffered pipeline, XCD-pinned bh, swapped QK^T, defer-max.
// ---------------------------------------------------------------------------
__global__ __launch_bounds__(512, 4)
void attn_kernel(const u16* __restrict__ qkv, const u16* __restrict__ Vt,
                 u16* __restrict__ attnout) {
  __shared__ __align__(16) u16 KV[2][2][64 * 64];   // [buf][K/V][row*64+col] 32 KB
  __shared__ __align__(16) u16 Ps[8][16 * 64];      // wave-private P, 16 KB

  const int tid = threadIdx.x;
  const int wv = tid >> 6, lane = tid & 63;
  const int lr = lane & 15, lg = lane >> 4;
  const int lin = (int)(blockIdx.y * gridDim.x + blockIdx.x);
  const int xcd = lin & 7, j = lin >> 3;
  const int bh = xcd * 4 + (j >> 4);
  const int pr = j & 15;
  const int b = bh >> 4, h = bh & 15;
  const size_t tokbase = (size_t)b * 2048;
  const int qhi = 31 - pr;
  const int qt = (wv < 4) ? qhi : pr;
  const int ws = wv & 3;
  const int qg = qt * 64 + ws * 16 + lr;

  bf16x8 qf[2];
#pragma unroll
  for (int ks = 0; ks < 2; ++ks)
    qf[ks] = *(const bf16x8*)(qkv + (tokbase + qt * 64 + ws * 16 + lr) * 3072 +
                              h * 64 + ks * 32 + lg * 8);

  f32x4 o[4] = {};
  float m = -1e30f, lp = 0.f;

  const u16* kg_base = qkv + tokbase * 3072 + 1024 + h * 64;
  const u16* vg_base = Vt + (size_t)bh * 64 * 2048;

  const int soff = tid * 16;
  const int srow = soff >> 7;
  const int scol = (soff & 127) ^ ((srow & 7) << 4);
  auto stage = [&](int bsel, int kt2) {
    stage16((char*)&KV[bsel][0][0] + wv * 1024,
            kg_base + (size_t)(kt2 * 64 + srow) * 3072 + (scol >> 1));
    stage16((char*)&KV[bsel][1][0] + wv * 1024,
            vg_base + (size_t)srow * 2048 + kt2 * 64 + (scol >> 1));
  };

  stage(0, 0);
  stage(1, 1);
  asm volatile("s_waitcnt vmcnt(2)\n\ts_barrier" ::: "memory");

  for (int kt = 0; kt <= qhi; ++kt) {
    if (kt <= qt) {
      const char* Ks = (const char*)&KV[kt & 1][0][0];
      const char* Vs = (const char*)&KV[kt & 1][1][0];

      f32x4 s[4] = {};
#pragma unroll
      for (int ks = 0; ks < 2; ++ks)
#pragma unroll
        for (int nt = 0; nt < 4; ++nt) {
          const int row = nt * 16 + lr;
          const bf16x8 kf = *(const bf16x8*)(Ks + row * 128 +
                                             ((ks * 64 + lg * 16) ^ ((lr & 7) << 4)));
          s[nt] = __builtin_amdgcn_mfma_f32_16x16x32_bf16(kf, qf[ks], s[nt], 0, 0, 0);
        }

      float pmax = -1e30f;
      const bool diag = (kt == qt);
#pragma unroll
      for (int nt = 0; nt < 4; ++nt)
#pragma unroll
        for (int r = 0; r < 4; ++r) {
          float v = s[nt][r] * SCALE2;
          if (diag) {
            const int kg = kt * 64 + nt * 16 + lg * 4 + r;
            v = (kg <= qg) ? v : -1e30f;
          }
          s[nt][r] = v;
          pmax = fmaxf(pmax, v);
        }

      if (!__all(pmax - m <= DEFER_THR)) {
        float mx = fmaxf(pmax, __shfl_xor(pmax, 16));
        mx = fmaxf(mx, __shfl_xor(mx, 32));
        const float mn = fmaxf(m, mx);
        const float alpha = fexp2(m - mn);
        m = mn;
        lp *= alpha;
#pragma unroll
        for (int r = 0; r < 4; ++r) {
          const float ar = __shfl(alpha, lg * 4 + r);
#pragma unroll
          for (int dt = 0; dt < 4; ++dt) o[dt][r] *= ar;
        }
      }

#pragma unroll
      for (int nt = 0; nt < 4; ++nt) {
        const float p0 = fexp2(s[nt][0] - m), p1 = fexp2(s[nt][1] - m);
        const float p2 = fexp2(s[nt][2] - m), p3 = fexp2(s[nt][3] - m);
        lp += (p0 + p1) + (p2 + p3);
        uint2 w;
        w.x = (u32)f2bf(p0) | ((u32)f2bf(p1) << 16);
        w.y = (u32)f2bf(p2) | ((u32)f2bf(p3) << 16);
        *(uint2*)((char*)&Ps[wv][0] + lr * 128 + ((nt * 32 + lg * 8) ^ ((lr & 7) << 4))) = w;
      }

      bf16x8 pf[2];
#pragma unroll
      for (int ks = 0; ks < 2; ++ks) {
        const int jp = (ks * 4 + lg) ^ (lr & 7);
        pf[ks] = *(const bf16x8*)(&Ps[wv][0] + lr * 64 + jp * 8);
      }
#pragma unroll
      for (int ks = 0; ks < 2; ++ks)
#pragma unroll
        for (int dt = 0; dt < 4; ++dt) {
          const int row = dt * 16 + lr;
          const bf16x8 vf = *(const bf16x8*)(Vs + row * 128 +
                                             ((ks * 64 + lg * 16) ^ ((lr & 7) << 4)));
          o[dt] = __builtin_amdgcn_mfma_f32_16x16x32_bf16(pf[ks], vf, o[dt], 0, 0, 0);
        }
    }

    __syncthreads();
    if (kt + 2 <= qhi) stage(kt & 1, kt + 2);
    asm volatile("s_barrier" ::: "memory");
  }

  float lsum = lp + __shfl_xor(lp, 16);
  lsum += __shfl_xor(lsum, 32);
#pragma unroll
  for (int r = 0; r < 4; ++r) {
    const float ld = __shfl(lsum, lg * 4 + r);
    const int tok = qt * 64 + ws * 16 + lg * 4 + r;
#pragma unroll
    for (int dt = 0; dt < 4; ++dt)
      attnout[(tokbase + tok) * 1024 + h * 64 + dt * 16 + lr] = f2bf(o[dt][r] / ld);
  }
}

// ---------------------------------------------------------------------------
extern "C" void kernel_launch(void* const* d_in, const int* in_sizes, int n_in,
                              void* d_out, int out_size, void* d_ws, size_t ws_size,
                              hipStream_t stream) {
  (void)in_sizes; (void)n_in; (void)ws_size;
  const float* x_in  = (const float*)d_in[0];
  const float* ln1_g = (const float*)d_in[2];
  const float* ln1_b = (const float*)d_in[3];
  const float* Wqkv  = (const float*)d_in[4];
  const float* Wout  = (const float*)d_in[5];
  const float* bout  = (const float*)d_in[6];
  const float* ln2_g = (const float*)d_in[7];
  const float* ln2_b = (const float*)d_in[8];
  const float* W1    = (const float*)d_in[9];
  const float* b1    = (const float*)d_in[10];
  const float* W2    = (const float*)d_in[11];
  const float* b2    = (const float*)d_in[12];
  float* x = (float*)d_out;   // residual stream lives in d_out

  char* ws = (char*)d_ws;
  size_t off = 0;
  auto alloc = [&](size_t bytes) -> void* {
    void* p = ws + off;
    off += (bytes + 255) & ~(size_t)255;
    return p;
  };
  u16* WqkvT = (u16*)alloc(4ull * 3072 * 1024 * 2);
  u16* WoutT = (u16*)alloc(4ull * 1024 * 1024 * 2);
  u16* W1T   = (u16*)alloc(4ull * 8192 * 1024 * 2);
  u16* W2T   = (u16*)alloc(4ull * 1024 * 4096 * 2);
  u16* y     = (u16*)alloc(4096ull * 1024 * 2);
  u16* qkvb  = (u16*)alloc(4096ull * 3072 * 2);
  u16* Vt    = (u16*)alloc(32ull * 64 * 2048 * 2);
  u16* attn  = (u16*)alloc(4096ull * 1024 * 2);
  u16* ff    = (u16*)alloc(4096ull * 4096 * 2);

  hipMemcpyAsync(x, x_in, (size_t)out_size * 4, hipMemcpyDeviceToDevice, stream);

  const dim3 tb(32, 8);
  wtrans_kernel<<<dim3(3072 / 32, 1024 / 32, 4), tb, 0, stream>>>(Wqkv, WqkvT, 1024, 3072, 0);
  wtrans_kernel<<<dim3(1024 / 32, 1024 / 32, 4), tb, 0, stream>>>(Wout, WoutT, 1024, 1024, 0);
  wtrans_kernel<<<dim3(8192 / 32, 1024 / 32, 4), tb, 0, stream>>>(W1, W1T, 1024, 8192, 1);
  wtrans_kernel<<<dim3(1024 / 32, 4096 / 32, 4), tb, 0, stream>>>(W2, W2T, 4096, 1024, 0);

  for (int l = 0; l < 4; ++l) {
    ln_kernel<<<4096, 256, 0, stream>>>(x, ln1_g + l * 1024, ln1_b + l * 1024, y);
    gemm3<0, 128, 128, 2, 2><<<dim3(3072 / 128, 4096 / 128), 256, 0, stream>>>(
        y, WqkvT + (size_t)l * 3072 * 1024, nullptr, nullptr, qkvb, 4096, 3072, 1024);
    vtrans_kernel<<<dim3(64, 2, 32), tb, 0, stream>>>(qkvb, Vt);
    attn_kernel<<<dim3(16, 32), 512, 0, stream>>>(qkvb, Vt, attn);
    gemm3<1, 128, 128, 2, 2><<<dim3(1024 / 128, 4096 / 128), 256, 0, stream>>>(
        attn, WoutT + (size_t)l * 1024 * 1024, x, bout + l * 1024, nullptr, 4096, 1024, 1024);
    ln_kernel<<<4096, 256, 0, stream>>>(x, ln2_g + l * 1024, ln2_b + l * 1024, y);
    gemm3<2, 256, 256, 2, 4><<<dim3(8192 / 256, 4096 / 256), 512, 0, stream>>>(
        y, W1T + (size_t)l * 8192 * 1024, nullptr, b1 + l * 8192, ff, 4096, 8192, 1024);
    gemm3<1, 128, 128, 2, 2><<<dim3(1024 / 128, 4096 / 128), 256, 0, stream>>>(
        ff, W2T + (size_t)l * 1024 * 4096, x, b2 + l * 1024, nullptr, 4096, 1024, 4096);
  }
}

// Round 11
// 1152.535 us; speedup vs baseline: 1.5199x; 1.0081x over previous
//
#include <hip/hip_runtime.h>

// ---------------------------------------------------------------------------
// Transformer (B=2, N=2048, D=1024, H=16, DH=64, DEPTH=4, FF=4, GEGLU, causal)
// R11: GEMM v4 — cross-tile ks-split pipeline. Per tile: issue ks1 reads,
// MFMA ks0 (reads drain under it), lgkm0+barrier (free buf), stage t+2,
// counted vmcnt(8) join, issue next tile's ks0 reads, MFMA ks1 (reads drain
// under it). LDS-read drain is never exposed. Attention (R9) unchanged.
// ---------------------------------------------------------------------------

typedef float f32x4 __attribute__((ext_vector_type(4)));
typedef __bf16 bf16x8 __attribute__((ext_vector_type(8)));
typedef unsigned short u16;
typedef unsigned int u32;

#define SCALE2 0.18033688011112042f   // DH^-0.5 * log2(e)
#define LN_EPS 1e-3f
#define DEFER_THR 8.0f                // log2-domain: P bounded by 2^8

__device__ __forceinline__ float fexp2(float x) { return __builtin_amdgcn_exp2f(x); }

__device__ __forceinline__ u16 f2bf(float f) {
  u32 u = __float_as_uint(f);
  u += 0x7fffu + ((u >> 16) & 1u);   // round-to-nearest-even
  return (u16)(u >> 16);
}

// async global->LDS, 16B/lane; lds base wave-uniform (HW adds lane*16)
__device__ __forceinline__ void stage16(void* lds_wave_base, const void* gsrc) {
  __builtin_amdgcn_global_load_lds((__attribute__((address_space(1))) void*)gsrc,
                                   (__attribute__((address_space(3))) void*)lds_wave_base,
                                   16, 0, 0);
}

// ---------------------------------------------------------------------------
// Weight transpose + cast: W f32 [L][K][N] -> WT bf16 [L][N][K].
// permMode=1 (W1): rows permuted so 16 a-cols / 16 gate-cols alternate.
// ---------------------------------------------------------------------------
__global__ void wtrans_kernel(const float* __restrict__ W, u16* __restrict__ WT,
                              int K, int N, int permMode) {
  __shared__ float tile[32][33];
  const int n0 = blockIdx.x * 32, k0 = blockIdx.y * 32;
  const float* Wl = W + (size_t)blockIdx.z * K * N;
  u16* WTl = WT + (size_t)blockIdx.z * K * N;
  const int tx = threadIdx.x, ty = threadIdx.y;
#pragma unroll
  for (int i = 0; i < 4; ++i)
    tile[ty + i * 8][tx] = Wl[(size_t)(k0 + ty + i * 8) * N + n0 + tx];
  __syncthreads();
#pragma unroll
  for (int i = 0; i < 4; ++i) {
    const int n = n0 + ty + i * 8;
    int orow;
    if (permMode) {
      orow = (n < 4096) ? (((n >> 4) << 5) + (n & 15))
                        : ((((n - 4096) >> 4) << 5) + 16 + (n & 15));
    } else {
      orow = n;
    }
    WTl[(size_t)orow * K + k0 + tx] = f2bf(tile[tx][ty + i * 8]);
  }
}

// V part of qkv -> per-(b,h) transposed V^T [bh][64 d][2048 tok] (bf16)
__global__ void vtrans_kernel(const u16* __restrict__ qkv, u16* __restrict__ Vt) {
  __shared__ u16 tile[32][33];
  const int t0 = blockIdx.x * 32, d0 = blockIdx.y * 32, bh = blockIdx.z;
  const int b = bh >> 4, h = bh & 15;
  const int tx = threadIdx.x, ty = threadIdx.y;
#pragma unroll
  for (int i = 0; i < 4; ++i)
    tile[ty + i * 8][tx] =
        qkv[((size_t)(b * 2048 + t0 + ty + i * 8)) * 3072 + 2048 + h * 64 + d0 + tx];
  __syncthreads();
#pragma unroll
  for (int i = 0; i < 4; ++i)
    Vt[((size_t)bh * 64 + d0 + ty + i * 8) * 2048 + t0 + tx] = tile[tx][ty + i * 8];
}

// ---------------------------------------------------------------------------
// LayerNorm: x f32 [4096][1024] -> y bf16
// ---------------------------------------------------------------------------
__global__ __launch_bounds__(256, 4)
void ln_kernel(const float* __restrict__ x, const float* __restrict__ g,
               const float* __restrict__ b, u16* __restrict__ y) {
  const int row = blockIdx.x, tid = threadIdx.x;
  const float4 v = ((const float4*)(x + (size_t)row * 1024))[tid];
  float s = v.x + v.y + v.z + v.w;
  float s2 = v.x * v.x + v.y * v.y + v.z * v.z + v.w * v.w;
#pragma unroll
  for (int off = 32; off > 0; off >>= 1) {
    s += __shfl_down(s, off);
    s2 += __shfl_down(s2, off);
  }
  __shared__ float ps[8];
  __shared__ float stats[2];
  const int wv = tid >> 6, lane = tid & 63;
  if (lane == 0) { ps[wv] = s; ps[wv + 4] = s2; }
  __syncthreads();
  if (tid == 0) {
    const float S = ps[0] + ps[1] + ps[2] + ps[3];
    const float S2 = ps[4] + ps[5] + ps[6] + ps[7];
    const float mu = S * (1.0f / 1024.0f);
    const float var = S2 * (1.0f / 1024.0f) - mu * mu;
    stats[0] = mu;
    stats[1] = rsqrtf(var + LN_EPS);
  }
  __syncthreads();
  const float mu = stats[0], rs = stats[1];
  const float4 gg = ((const float4*)g)[tid];
  const float4 bb = ((const float4*)b)[tid];
  ushort4 ov;
  ov.x = f2bf((v.x - mu) * rs * gg.x + bb.x);
  ov.y = f2bf((v.y - mu) * rs * gg.y + bb.y);
  ov.z = f2bf((v.z - mu) * rs * gg.z + bb.z);
  ov.w = f2bf((v.w - mu) * rs * gg.w + bb.w);
  ((ushort4*)(y + (size_t)row * 1024))[tid] = ov;
}

// ---------------------------------------------------------------------------
// GEMM v4: C[M,N] = A[M,K] * B^T[N,K], bf16, fp32 acc, BK=64, 2 LDS buffers.
// Cross-tile ks-split schedule (per tile t, buf c=t&1):
//   R1(t): issue ks1 ds_reads (MT+NT)            [12 or 8]
//   M0(t): MFMA ks0 (R1 drains underneath)
//   lgkm(0)+s_barrier                            -> buf c free
//   stage(t+2 -> c)                              [8 global_load_lds]
//   vmcnt(8)+s_barrier (counted; t+2 stays in flight)  [vmcnt(0) at tail]
//   R0(t+1): issue next ks0 ds_reads from buf ~c
//   M1(t): MFMA ks1 (R0 drains underneath)
// LDS-read drain is always covered by an MFMA cluster; 2 barriers/tile.
// ---------------------------------------------------------------------------
template <int EPI, int BM, int BN, int WM, int WN>
__global__ __launch_bounds__(WM * WN * 64, 2)
void gemm4(const u16* __restrict__ A, const u16* __restrict__ B,
           float* __restrict__ resid, const float* __restrict__ bias,
           u16* __restrict__ out, int M, int N, int K) {
  constexpr int NTHR = WM * WN * 64;
  constexpr int MT = BM / WM / 16;
  constexpr int NT = BN / WN / 16;
  __shared__ __align__(16) u16 lds[2][(BM + BN) * 64];

  const int tid = threadIdx.x;
  const int wv = tid >> 6, lane = tid & 63;
  const int lr = lane & 15, lg = lane >> 4;
  const int wmi = wv / WN, wni = wv % WN;
  const int RB0 = wmi * (BM / WM), CB0 = wni * (BN / WN);

  const int nwg = (int)(gridDim.x * gridDim.y);
  int id = (int)(blockIdx.y * gridDim.x + blockIdx.x);
  id = (id & 7) * (nwg >> 3) + (id >> 3);
  const int m0 = (id / (int)gridDim.x) * BM, n0 = (id % (int)gridDim.x) * BN;

  auto stage = [&](int bsel, int k0) {
    u16* dstA = &lds[bsel][0];
    u16* dstB = &lds[bsel][BM * 64];
#pragma unroll
    for (int rnd = 0; rnd < (BM * 128) / (NTHR * 16); ++rnd) {
      const int base = rnd * (NTHR * 16) + wv * 1024;
      const int off = base + lane * 16;
      const int row = off >> 7;
      const int k2 = (off & 127) ^ ((row & 7) << 4);
      stage16((char*)dstA + base, A + (size_t)(m0 + row) * K + k0 + (k2 >> 1));
    }
#pragma unroll
    for (int rnd = 0; rnd < (BN * 128) / (NTHR * 16); ++rnd) {
      const int base = rnd * (NTHR * 16) + wv * 1024;
      const int off = base + lane * 16;
      const int row = off >> 7;
      const int k2 = (off & 127) ^ ((row & 7) << 4);
      stage16((char*)dstB + base, B + (size_t)(n0 + row) * K + k0 + (k2 >> 1));
    }
  };

  f32x4 acc[MT][NT] = {};
  bf16x8 afr0[MT], bfr0[NT], afr1[MT], bfr1[NT];

  // ds_read one ks-half's fragments from buffer bsel into (af, bf)
  auto rd = [&](int bsel, int ks, bf16x8 (&af)[MT], bf16x8 (&bf)[NT]) {
    const char* As = (const char*)&lds[bsel][0];
    const char* Bs = (const char*)&lds[bsel][BM * 64];
#pragma unroll
    for (int mt = 0; mt < MT; ++mt) {
      const int row = RB0 + mt * 16 + lr;
      af[mt] = *(const bf16x8*)(As + row * 128 + ((ks * 64 + lg * 16) ^ ((lr & 7) << 4)));
    }
#pragma unroll
    for (int nt = 0; nt < NT; ++nt) {
      const int row = CB0 + nt * 16 + lr;
      bf[nt] = *(const bf16x8*)(Bs + row * 128 + ((ks * 64 + lg * 16) ^ ((lr & 7) << 4)));
    }
  };

  const int nT = K >> 6;
  stage(0, 0);
  stage(1, 64);
  asm volatile("s_waitcnt vmcnt(8)\n\ts_barrier" ::: "memory");  // tile0 landed
  rd(0, 0, afr0, bfr0);                                          // R0(0)
  __builtin_amdgcn_sched_barrier(0);

  for (int t = 0; t < nT; ++t) {
    const int c = t & 1;
    rd(c, 1, afr1, bfr1);                 // R1(t) issue
    __builtin_amdgcn_sched_barrier(0);
    // M0(t): ks0 MFMAs (compiler waits only on afr0/bfr0; R1 drains under)
    __builtin_amdgcn_s_setprio(1);
#pragma unroll
    for (int mt = 0; mt < MT; ++mt)
#pragma unroll
      for (int nt = 0; nt < NT; ++nt)
        acc[mt][nt] = __builtin_amdgcn_mfma_f32_16x16x32_bf16(
            afr0[mt], bfr0[nt], acc[mt][nt], 0, 0, 0);
    __builtin_amdgcn_s_setprio(0);
    __builtin_amdgcn_sched_barrier(0);
    // all reads of buf c complete -> free it for staging
    asm volatile("s_waitcnt lgkmcnt(0)\n\ts_barrier" ::: "memory");
    __builtin_amdgcn_sched_barrier(0);
    if (t + 2 < nT) stage(c, (t + 2) * 64);
    if (t + 1 < nT) {
      // counted join: tile t+1 landed, tile t+2 (if staged) stays in flight
      if (t + 2 < nT)
        asm volatile("s_waitcnt vmcnt(8)\n\ts_barrier" ::: "memory");
      else
        asm volatile("s_waitcnt vmcnt(0)\n\ts_barrier" ::: "memory");
      rd(c ^ 1, 0, afr0, bfr0);           // R0(t+1) issue
      __builtin_amdgcn_sched_barrier(0);
    }
    // M1(t): ks1 MFMAs (R0(t+1) drains under)
    __builtin_amdgcn_s_setprio(1);
#pragma unroll
    for (int mt = 0; mt < MT; ++mt)
#pragma unroll
      for (int nt = 0; nt < NT; ++nt)
        acc[mt][nt] = __builtin_amdgcn_mfma_f32_16x16x32_bf16(
            afr1[mt], bfr1[nt], acc[mt][nt], 0, 0, 0);
    __builtin_amdgcn_s_setprio(0);
  }

  // C/D: m = m0 + RB0 + mt*16 + lg*4 + r ; n = n0 + CB0 + nt*16 + lr
  if (EPI == 0) {
#pragma unroll
    for (int mt = 0; mt < MT; ++mt)
#pragma unroll
      for (int nt = 0; nt < NT; ++nt) {
        const int n = n0 + CB0 + nt * 16 + lr;
#pragma unroll
        for (int r = 0; r < 4; ++r) {
          const int m = m0 + RB0 + mt * 16 + lg * 4 + r;
          out[(size_t)m * N + n] = f2bf(acc[mt][nt][r]);
        }
      }
  } else if (EPI == 1) {
    float bs[NT];
#pragma unroll
    for (int nt = 0; nt < NT; ++nt) bs[nt] = bias[n0 + CB0 + nt * 16 + lr];
#pragma unroll
    for (int mt = 0; mt < MT; ++mt)
#pragma unroll
      for (int nt = 0; nt < NT; ++nt) {
        const int n = n0 + CB0 + nt * 16 + lr;
#pragma unroll
        for (int r = 0; r < 4; ++r) {
          const int m = m0 + RB0 + mt * 16 + lg * 4 + r;
          resid[(size_t)m * N + n] += acc[mt][nt][r] + bs[nt];
        }
      }
  } else {
#pragma unroll
    for (int pt = 0; pt < NT / 2; ++pt) {
      const int colA = ((n0 + CB0 + pt * 32) >> 5) * 16 + lr;
      const float ba = bias[colA];
      const float bg = bias[4096 + colA];
#pragma unroll
      for (int mt = 0; mt < MT; ++mt)
#pragma unroll
        for (int r = 0; r < 4; ++r) {
          const int m = m0 + RB0 + mt * 16 + lg * 4 + r;
          const float a = acc[mt][2 * pt][r] + ba;
          const float g = acc[mt][2 * pt + 1][r] + bg;
          const float gl = 0.5f * g * (1.0f + erff(g * 0.70710678118654752f));
          out[(size_t)m * 4096 + colA] = f2bf(a * gl);
        }
    }
  }
}

// ---------------------------------------------------------------------------
// Causal flash attention (R9, unchanged): LDS-staged K/V shared by 8 waves,
// double-buffered pipeline, XCD-pinned bh, swapped QK^T, defer-max.
// ---------------------------------------------------------------------------
__global__ __launch_bounds__(512, 4)
void attn_kernel(const u16* __restrict__ qkv, const u16* __restrict__ Vt,
                 u16* __restrict__ attnout) {
  __shared__ __align__(16) u16 KV[2][2][64 * 64];   // [buf][K/V][row*64+col] 32 KB
  __shared__ __align__(16) u16 Ps[8][16 * 64];      // wave-private P, 16 KB

  const int tid = threadIdx.x;
  const int wv = tid >> 6, lane = tid & 63;
  const int lr = lane & 15, lg = lane >> 4;
  const int lin = (int)(blockIdx.y * gridDim.x + blockIdx.x);
  const int xcd = lin & 7, j = lin >> 3;
  const int bh = xcd * 4 + (j >> 4);
  const int pr = j & 15;
  const int b = bh >> 4, h = bh & 15;
  const size_t tokbase = (size_t)b * 2048;
  const int qhi = 31 - pr;
  const int qt = (wv < 4) ? qhi : pr;
  const int ws = wv & 3;
  const int qg = qt * 64 + ws * 16 + lr;

  bf16x8 qf[2];
#pragma unroll
  for (int ks = 0; ks < 2; ++ks)
    qf[ks] = *(const bf16x8*)(qkv + (tokbase + qt * 64 + ws * 16 + lr) * 3072 +
                              h * 64 + ks * 32 + lg * 8);

  f32x4 o[4] = {};
  float m = -1e30f, lp = 0.f;

  const u16* kg_base = qkv + tokbase * 3072 + 1024 + h * 64;
  const u16* vg_base = Vt + (size_t)bh * 64 * 2048;

  const int soff = tid * 16;
  const int srow = soff >> 7;
  const int scol = (soff & 127) ^ ((srow & 7) << 4);
  auto stage = [&](int bsel, int kt2) {
    stage16((char*)&KV[bsel][0][0] + wv * 1024,
            kg_base + (size_t)(kt2 * 64 + srow) * 3072 + (scol >> 1));
    stage16((char*)&KV[bsel][1][0] + wv * 1024,
            vg_base + (size_t)srow * 2048 + kt2 * 64 + (scol >> 1));
  };

  stage(0, 0);
  stage(1, 1);
  asm volatile("s_waitcnt vmcnt(2)\n\ts_barrier" ::: "memory");

  for (int kt = 0; kt <= qhi; ++kt) {
    if (kt <= qt) {
      const char* Ks = (const char*)&KV[kt & 1][0][0];
      const char* Vs = (const char*)&KV[kt & 1][1][0];

      f32x4 s[4] = {};
#pragma unroll
      for (int ks = 0; ks < 2; ++ks)
#pragma unroll
        for (int nt = 0; nt < 4; ++nt) {
          const int row = nt * 16 + lr;
          const bf16x8 kf = *(const bf16x8*)(Ks + row * 128 +
                                             ((ks * 64 + lg * 16) ^ ((lr & 7) << 4)));
          s[nt] = __builtin_amdgcn_mfma_f32_16x16x32_bf16(kf, qf[ks], s[nt], 0, 0, 0);
        }

      float pmax = -1e30f;
      const bool diag = (kt == qt);
#pragma unroll
      for (int nt = 0; nt < 4; ++nt)
#pragma unroll
        for (int r = 0; r < 4; ++r) {
          float v = s[nt][r] * SCALE2;
          if (diag) {
            const int kg = kt * 64 + nt * 16 + lg * 4 + r;
            v = (kg <= qg) ? v : -1e30f;
          }
          s[nt][r] = v;
          pmax = fmaxf(pmax, v);
        }

      if (!__all(pmax - m <= DEFER_THR)) {
        float mx = fmaxf(pmax, __shfl_xor(pmax, 16));
        mx = fmaxf(mx, __shfl_xor(mx, 32));
        const float mn = fmaxf(m, mx);
        const float alpha = fexp2(m - mn);
        m = mn;
        lp *= alpha;
#pragma unroll
        for (int r = 0; r < 4; ++r) {
          const float ar = __shfl(alpha, lg * 4 + r);
#pragma unroll
          for (int dt = 0; dt < 4; ++dt) o[dt][r] *= ar;
        }
      }

#pragma unroll
      for (int nt = 0; nt < 4; ++nt) {
        const float p0 = fexp2(s[nt][0] - m), p1 = fexp2(s[nt][1] - m);
        const float p2 = fexp2(s[nt][2] - m), p3 = fexp2(s[nt][3] - m);
        lp += (p0 + p1) + (p2 + p3);
        uint2 w;
        w.x = (u32)f2bf(p0) | ((u32)f2bf(p1) << 16);
        w.y = (u32)f2bf(p2) | ((u32)f2bf(p3) << 16);
        *(uint2*)((char*)&Ps[wv][0] + lr * 128 + ((nt * 32 + lg * 8) ^ ((lr & 7) << 4))) = w;
      }

      bf16x8 pf[2];
#pragma unroll
      for (int ks = 0; ks < 2; ++ks) {
        const int jp = (ks * 4 + lg) ^ (lr & 7);
        pf[ks] = *(const bf16x8*)(&Ps[wv][0] + lr * 64 + jp * 8);
      }
#pragma unroll
      for (int ks = 0; ks < 2; ++ks)
#pragma unroll
        for (int dt = 0; dt < 4; ++dt) {
          const int row = dt * 16 + lr;
          const bf16x8 vf = *(const bf16x8*)(Vs + row * 128 +
                                             ((ks * 64 + lg * 16) ^ ((lr & 7) << 4)));
          o[dt] = __builtin_amdgcn_mfma_f32_16x16x32_bf16(pf[ks], vf, o[dt], 0, 0, 0);
        }
    }

    __syncthreads();
    if (kt + 2 <= qhi) stage(kt & 1, kt + 2);
    asm volatile("s_barrier" ::: "memory");
  }

  float lsum = lp + __shfl_xor(lp, 16);
  lsum += __shfl_xor(lsum, 32);
#pragma unroll
  for (int r = 0; r < 4; ++r) {
    const float ld = __shfl(lsum, lg * 4 + r);
    const int tok = qt * 64 + ws * 16 + lg * 4 + r;
#pragma unroll
    for (int dt = 0; dt < 4; ++dt)
      attnout[(tokbase + tok) * 1024 + h * 64 + dt * 16 + lr] = f2bf(o[dt][r] / ld);
  }
}

// ---------------------------------------------------------------------------
extern "C" void kernel_launch(void* const* d_in, const int* in_sizes, int n_in,
                              void* d_out, int out_size, void* d_ws, size_t ws_size,
                              hipStream_t stream) {
  (void)in_sizes; (void)n_in; (void)ws_size;
  const float* x_in  = (const float*)d_in[0];
  const float* ln1_g = (const float*)d_in[2];
  const float* ln1_b = (const float*)d_in[3];
  const float* Wqkv  = (const float*)d_in[4];
  const float* Wout  = (const float*)d_in[5];
  const float* bout  = (const float*)d_in[6];
  const float* ln2_g = (const float*)d_in[7];
  const float* ln2_b = (const float*)d_in[8];
  const float* W1    = (const float*)d_in[9];
  const float* b1    = (const float*)d_in[10];
  const float* W2    = (const float*)d_in[11];
  const float* b2    = (const float*)d_in[12];
  float* x = (float*)d_out;   // residual stream lives in d_out

  char* ws = (char*)d_ws;
  size_t off = 0;
  auto alloc = [&](size_t bytes) -> void* {
    void* p = ws + off;
    off += (bytes + 255) & ~(size_t)255;
    return p;
  };
  u16* WqkvT = (u16*)alloc(4ull * 3072 * 1024 * 2);
  u16* WoutT = (u16*)alloc(4ull * 1024 * 1024 * 2);
  u16* W1T   = (u16*)alloc(4ull * 8192 * 1024 * 2);
  u16* W2T   = (u16*)alloc(4ull * 1024 * 4096 * 2);
  u16* y     = (u16*)alloc(4096ull * 1024 * 2);
  u16* qkvb  = (u16*)alloc(4096ull * 3072 * 2);
  u16* Vt    = (u16*)alloc(32ull * 64 * 2048 * 2);
  u16* attn  = (u16*)alloc(4096ull * 1024 * 2);
  u16* ff    = (u16*)alloc(4096ull * 4096 * 2);

  hipMemcpyAsync(x, x_in, (size_t)out_size * 4, hipMemcpyDeviceToDevice, stream);

  const dim3 tb(32, 8);
  wtrans_kernel<<<dim3(3072 / 32, 1024 / 32, 4), tb, 0, stream>>>(Wqkv, WqkvT, 1024, 3072, 0);
  wtrans_kernel<<<dim3(1024 / 32, 1024 / 32, 4), tb, 0, stream>>>(Wout, WoutT, 1024, 1024, 0);
  wtrans_kernel<<<dim3(8192 / 32, 1024 / 32, 4), tb, 0, stream>>>(W1, W1T, 1024, 8192, 1);
  wtrans_kernel<<<dim3(1024 / 32, 4096 / 32, 4), tb, 0, stream>>>(W2, W2T, 4096, 1024, 0);

  for (int l = 0; l < 4; ++l) {
    ln_kernel<<<4096, 256, 0, stream>>>(x, ln1_g + l * 1024, ln1_b + l * 1024, y);
    gemm4<0, 128, 128, 2, 2><<<dim3(3072 / 128, 4096 / 128), 256, 0, stream>>>(
        y, WqkvT + (size_t)l * 3072 * 1024, nullptr, nullptr, qkvb, 4096, 3072, 1024);
    vtrans_kernel<<<dim3(64, 2, 32), tb, 0, stream>>>(qkvb, Vt);
    attn_kernel<<<dim3(16, 32), 512, 0, stream>>>(qkvb, Vt, attn);
    gemm4<1, 128, 128, 2, 2><<<dim3(1024 / 128, 4096 / 128), 256, 0, stream>>>(
        attn, WoutT + (size_t)l * 1024 * 1024, x, bout + l * 1024, nullptr, 4096, 1024, 1024);
    ln_kernel<<<4096, 256, 0, stream>>>(x, ln2_g + l * 1024, ln2_b + l * 1024, y);
    gemm4<2, 256, 256, 2, 4><<<dim3(8192 / 256, 4096 / 256), 512, 0, stream>>>(
        y, W1T + (size_t)l * 8192 * 1024, nullptr, b1 + l * 8192, ff, 4096, 8192, 1024);
    gemm4<1, 128, 128, 2, 2><<<dim3(1024 / 128, 4096 / 128), 256, 0, stream>>>(
        ff, W2T + (size_t)l * 1024 * 4096, x, b2 + l * 1024, nullptr, 4096, 1024, 4096);
  }
}